// Round 15
// baseline (460.209 us; speedup 1.0000x reference)
//
#include <hip/hip_runtime.h>
#include <hip/hip_bf16.h>
#include <hip/hip_fp16.h>

#define N_NODES 128000
#define E_EDGES 2048000
#define G_GRAPHS 512
#define D_IN 12
#define D_H 64
#define N_CLS 10
#define BN_EPS 1e-5f
#define NB 1000        // buckets = dst >> 7 (128-node ranges)
#define BCAP 2560      // fixed records per bucket region
#define TILE 2048      // edges per k_bin block (1000 blocks; 8192 gave 1 block/CU = TLP-starved)
#define NPW 8          // nodes per wave in gine64
#define NPW12 4        // nodes per wave in gine12

typedef _Float16 h2vec __attribute__((ext_vector_type(2)));
typedef _Float16 h4vec __attribute__((ext_vector_type(4)));

__device__ __forceinline__ unsigned char f32_to_fp8(float v) {
    return (unsigned char)(__builtin_amdgcn_cvt_pk_fp8_f32(v, v, 0, false) & 0xff);
}

// ---------------- CSR build: bucket counting-sort ----------------
// Sort-then-write (r8): stage records written in block-local bucket-sorted order.
// TILE=2048 (r15): 1000 blocks, 25KB LDS -> multiple blocks/CU, 4x wave-level TLP
// vs the 250-block / 61KB / 1-block-per-CU configuration.

__global__ __launch_bounds__(256) void k_bin(const int* __restrict__ src, const int* __restrict__ dst,
                                             const float2* __restrict__ attr, int* __restrict__ gcount,
                                             int2* __restrict__ stage) {
    __shared__ int hist[NB];
    __shared__ int base_s[NB];
    __shared__ int bscan[NB];                // block-local sorted start per bucket
    __shared__ int rk[TILE];                 // packed b(10)<<20 | dstLow(7)<<13 | rank(13)
    __shared__ unsigned short sorted[TILE];  // sorted position -> edge idx
    __shared__ int psum[256];
    const int t = threadIdx.x;
    const int e0 = blockIdx.x * TILE;
    for (int i = t; i < NB; i += 256) hist[i] = 0;
    __syncthreads();
    for (int i = t; i < TILE; i += 256) {
        int d = dst[e0 + i];
        int b = d >> 7;
        int r = atomicAdd(&hist[b], 1);
        rk[i] = (b << 20) | ((d & 127) << 13) | r;
    }
    __syncthreads();
    // block-local exclusive scan over NB buckets (each thread owns 4)
    int h0 = (t * 4     < NB) ? hist[t * 4]     : 0;
    int h1 = (t * 4 + 1 < NB) ? hist[t * 4 + 1] : 0;
    int h2 = (t * 4 + 2 < NB) ? hist[t * 4 + 2] : 0;
    int h3 = (t * 4 + 3 < NB) ? hist[t * 4 + 3] : 0;
    int s = h0 + h1 + h2 + h3;
    psum[t] = s;
    __syncthreads();
    for (int off = 1; off < 256; off <<= 1) {
        int x = 0;
        if (t >= off) x = psum[t - off];
        __syncthreads();
        psum[t] += x;
        __syncthreads();
    }
    int base = psum[t] - s;  // exclusive
    if (t * 4     < NB) bscan[t * 4]     = base;
    if (t * 4 + 1 < NB) bscan[t * 4 + 1] = base + h0;
    if (t * 4 + 2 < NB) bscan[t * 4 + 2] = base + h0 + h1;
    if (t * 4 + 3 < NB) bscan[t * 4 + 3] = base + h0 + h1 + h2;
    for (int i = t; i < NB; i += 256) {
        int cb = hist[i];
        base_s[i] = i * BCAP + ((cb > 0) ? atomicAdd(&gcount[i], cb) : 0);
    }
    __syncthreads();
    // inverse permutation: sorted position -> edge index
    for (int i = t; i < TILE; i += 256) {
        int pr = rk[i];
        int b = pr >> 20, r = pr & 8191;
        sorted[bscan[b] + r] = (unsigned short)i;
    }
    __syncthreads();
    // write stage in sorted order: contiguous runs per bucket
    for (int p = t; p < TILE; p += 256) {
        int i = sorted[p];
        int pr = rk[i];
        int b = pr >> 20, dl = (pr >> 13) & 127, r = pr & 8191;
        float2 a = attr[e0 + i];
        __half2 h2 = __floats2half2_rn(a.x, a.y);
        stage[base_s[b] + r] = make_int2(src[e0 + i] | (dl << 17), *(int*)&h2);
    }
}

__global__ __launch_bounds__(256) void k_bscan(const int* __restrict__ gcount, int* __restrict__ bbase,
                                               int* __restrict__ offsets) {
    __shared__ int sm[256];
    const int t = threadIdx.x;
    int c0 = gcount[t * 4], c1 = gcount[t * 4 + 1], c2 = gcount[t * 4 + 2], c3 = gcount[t * 4 + 3];
    int s = c0 + c1 + c2 + c3;
    sm[t] = s;
    __syncthreads();
    for (int off = 1; off < 256; off <<= 1) {
        int x = 0;
        if (t >= off) x = sm[t - off];
        __syncthreads();
        sm[t] += x;
        __syncthreads();
    }
    int base = sm[t] - s;  // exclusive
    if (t * 4 < NB)     bbase[t * 4]     = base;
    if (t * 4 + 1 < NB) bbase[t * 4 + 1] = base + c0;
    if (t * 4 + 2 < NB) bbase[t * 4 + 2] = base + c0 + c1;
    if (t * 4 + 3 < NB) bbase[t * 4 + 3] = base + c0 + c1 + c2;
    if (t == 255) offsets[N_NODES] = sm[255];
}

__global__ __launch_bounds__(256) void k_final(const int* __restrict__ gcount, const int* __restrict__ bbase,
                                               const int2* __restrict__ stage,
                                               int* __restrict__ offsets, int2* __restrict__ edges) {
    __shared__ int2 recs[BCAP];   // 20.5 KB
    __shared__ int cnt[128];
    __shared__ int incl[128];
    const int b = blockIdx.x, t = threadIdx.x;
    const int count = gcount[b];
    const int base = bbase[b];
    if (t < 128) cnt[t] = 0;
    __syncthreads();
    for (int i = t; i < count; i += 256) {
        int2 r = stage[b * BCAP + i];
        recs[i] = r;
        atomicAdd(&cnt[(r.x >> 17) & 127], 1);
    }
    __syncthreads();
    if (t < 128) incl[t] = cnt[t];
    __syncthreads();
    for (int off = 1; off < 128; off <<= 1) {   // parallel Hillis-Steele over 128
        int x = 0;
        if (t >= off && t < 128) x = incl[t - off];
        __syncthreads();
        if (t < 128) incl[t] += x;
        __syncthreads();
    }
    if (t < 128) {
        int ex = incl[t] - cnt[t];
        offsets[b * 128 + t] = base + ex;
        cnt[t] = ex;   // becomes the placement cursor
    }
    __syncthreads();
    for (int i = t; i < count; i += 256) {
        int2 r = recs[i];
        int dl = (r.x >> 17) & 127;
        int p = atomicAdd(&cnt[dl], 1);
        edges[base + p] = make_int2(r.x & 0x1FFFF, r.y);
    }
}

// pack x [N,12] fp32 -> [N+1,16] fp16 (channels 12..15 = 0); row N = sentinel -3e4
__global__ __launch_bounds__(256) void k_pack_x(const float* __restrict__ x, __half* __restrict__ x16) {
    int idx = blockIdx.x * 256 + threadIdx.x;
    if (idx >= (N_NODES + 1) * 16) return;
    int n = idx >> 4, ch = idx & 15;
    float v = (n == N_NODES) ? -30000.f : ((ch < D_IN) ? x[n * D_IN + ch] : 0.f);
    x16[idx] = __float2half(v);
}

// ---------------- Layer 1 (12-dim input, 64-dim output; fp16+fp8 out) ----------------
// 8 edges per dword load (32B row = 8 dwords); lane l = edge-slot (l>>3), channel-pair (l&7).
// r3-proven load structure (FROZEN — restructuring failed 3x: r4/r5/r11).
__global__ __launch_bounds__(256) void k_gine12(
    const float* __restrict__ x, const __half* __restrict__ x16,
    __half* __restrict__ hout, unsigned char* __restrict__ hout8,
    const int* __restrict__ off, const int2* __restrict__ edges,
    const float* __restrict__ We1, const float* __restrict__ be1,
    const float* __restrict__ W1, const float* __restrict__ b1,
    const float* __restrict__ g1, const float* __restrict__ bt1,
    const float* __restrict__ rm1, const float* __restrict__ rv1,
    const float* __restrict__ Wr, const float* __restrict__ br) {
    __shared__ float W1lds[D_IN * 64];
    __shared__ float Wrlds[D_IN * 64];
    __shared__ float uacc[4][16];
    __shared__ float u_lds[4][D_IN];
    __shared__ float x_lds[4][D_IN];
    const int t = threadIdx.x, w = t >> 6, c = t & 63;
    const int asb = (c >> 3) << 2;    // bpermute base: edge-slot
    const int dwoff = (c & 7) << 2;   // dword byte offset within 32B row
    const int ch0 = (c & 7) << 1;     // this lane's channel pair
    for (int i = t; i < D_IN * 64; i += 256) {
        W1lds[i] = W1[i];
        Wrlds[i] = Wr[i];
    }
    h2vec wp0 = {(_Float16)0.f, (_Float16)0.f}, wp1 = wp0;
    float bp0 = 0.f, bp1 = 0.f;
    if (ch0 < D_IN)     { wp0[0] = (_Float16)We1[ch0];     wp0[1] = (_Float16)We1[D_IN + ch0];     bp0 = be1[ch0]; }
    if (ch0 + 1 < D_IN) { wp1[0] = (_Float16)We1[ch0 + 1]; wp1[1] = (_Float16)We1[D_IN + ch0 + 1]; bp1 = be1[ch0 + 1]; }
    const float sj = g1[c] * rsqrtf(rv1[c] + BN_EPS);
    const float cj = (b1[c] - rm1[c]) * sj + bt1[c];
    const float brj = br[c];
    __syncthreads();

    // XCD swizzle: 8000 blocks = 8 XCDs x 1000; same-XCD blocks -> contiguous nodes
    const int swz = (blockIdx.x & 7) * 1000 + (blockIdx.x >> 3);
    const int wbase = (swz * 4 + w) * NPW12;
    for (int nn = 0; nn < NPW12; ++nn) {
        const int n = wbase + nn;
        const int rs = off[n], re = off[n + 1];
        float a0 = 0.f, a1 = 0.f;
        for (int base = rs; base < re; base += 64) {
            const int cnt = min(64, re - base);
            int2 rec = make_int2(N_NODES, 0);
            if (c < cnt) rec = edges[base + c];
            for (int j0 = 0; j0 < cnt; j0 += 16) {
                const int ab = (j0 << 2) + asb;
                int s0 = __builtin_amdgcn_ds_bpermute(ab,      rec.x);
                int s1 = __builtin_amdgcn_ds_bpermute(ab + 32, rec.x);
                int e0 = __builtin_amdgcn_ds_bpermute(ab,      rec.y);
                int e1 = __builtin_amdgcn_ds_bpermute(ab + 32, rec.y);
                int ld0 = *(const int*)((const char*)x16 + ((s0 << 5) + dwoff));
                int ld1 = *(const int*)((const char*)x16 + ((s1 << 5) + dwoff));
                {
                    h2vec hv = __builtin_bit_cast(h2vec, ld0);
                    h2vec av = __builtin_bit_cast(h2vec, e0);
                    float q0 = __builtin_amdgcn_fdot2(av, wp0, bp0, false);
                    float q1 = __builtin_amdgcn_fdot2(av, wp1, bp1, false);
                    a0 += fmaxf((float)hv[0] + q0, 0.f);
                    a1 += fmaxf((float)hv[1] + q1, 0.f);
                }
                {
                    h2vec hv = __builtin_bit_cast(h2vec, ld1);
                    h2vec av = __builtin_bit_cast(h2vec, e1);
                    float q0 = __builtin_amdgcn_fdot2(av, wp0, bp0, false);
                    float q1 = __builtin_amdgcn_fdot2(av, wp1, bp1, false);
                    a0 += fmaxf((float)hv[0] + q0, 0.f);
                    a1 += fmaxf((float)hv[1] + q1, 0.f);
                }
            }
        }
        // fold 8 edge-slot groups (lane bits 3,4,5)
        a0 += __shfl_xor(a0, 8);  a1 += __shfl_xor(a1, 8);
        a0 += __shfl_xor(a0, 16); a1 += __shfl_xor(a1, 16);
        a0 += __shfl_xor(a0, 32); a1 += __shfl_xor(a1, 32);
        uacc[w][ch0] = a0;        // duplicate writers, same value
        uacc[w][ch0 + 1] = a1;
        if (c < D_IN) {
            float xc = x[(size_t)n * D_IN + c];
            x_lds[w][c] = xc;
            u_lds[w][c] = xc + uacc[w][c];
        }
        float z = 0.f, r = 0.f;
#pragma unroll
        for (int k = 0; k < D_IN; ++k) {
            z = fmaf(u_lds[w][k], W1lds[k * 64 + c], z);
            r = fmaf(x_lds[w][k], Wrlds[k * 64 + c], r);
        }
        float v = fmaxf(fmaf(z, sj, cj), 0.f) + r + brj;
        hout[(size_t)n * 64 + c] = __float2half(v);
        hout8[(size_t)n * 64 + c] = f32_to_fp8(v);
    }
}

// ---------------- Layers 2/3: fp8 gather, depth-1 pipeline + conditional early chunk-1 ----------------
// Lane l = edge-slot (l>>4), channel-quad (l&15). Loaded dword IS the accumulation layout.
// Chunk-0 (slots 0-15) prefetched one node ahead (r10 ping-pong). Chunk-1 (slots 16-31)
// issued EARLY only when deg>16 (wave-uniform branch) so its gather latency hides under
// chunk-0's consume; zero added work for deg<=16 nodes. Sentinel-killed tails (r7-verified).
__global__ __launch_bounds__(256) void k_gine64(
    const __half* __restrict__ hin, const unsigned char* __restrict__ hin8,
    __half* __restrict__ hout, unsigned char* __restrict__ hout8,
    const int* __restrict__ off, const int2* __restrict__ edges,
    const float* __restrict__ We, const float* __restrict__ be,
    const float* __restrict__ W, const float* __restrict__ b,
    const float* __restrict__ g, const float* __restrict__ bt,
    const float* __restrict__ rm, const float* __restrict__ rv) {
    __shared__ _Float16 WtL[64][68];   // transposed W, fp16
    __shared__ _Float16 uL[4][64];
    const int t = threadIdx.x, w = t >> 6, c = t & 63;
    for (int i = t; i < 4096; i += 256) {
        int k = i >> 6, cc = i & 63;
        WtL[cc][k] = (_Float16)W[i];   // W[k*64+cc]
    }
    const int asb   = (c >> 4) << 2;   // bpermute base: edge-slot
    const int dwoff = (c & 15) << 2;   // dword byte offset within 64B row
    const int q4    = (c & 15) << 2;   // base channel of this lane's quad
    h2vec weq[4];
    float beq[4];
#pragma unroll
    for (int j = 0; j < 4; ++j) {
        weq[j][0] = (_Float16)We[q4 + j];
        weq[j][1] = (_Float16)We[64 + q4 + j];
        beq[j] = be[q4 + j];
    }
    const float sj = g[c] * rsqrtf(rv[c] + BN_EPS);
    const float cj = (b[c] - rm[c]) * sj + bt[c];
    __syncthreads();

    // XCD swizzle: 4000 blocks = 8 XCDs x 500; same-XCD blocks -> contiguous nodes
    const int swz = (blockIdx.x & 7) * 500 + (blockIdx.x >> 3);
    const int wbase = (swz * 4 + w) * NPW;

    int offv[NPW + 1];
#pragma unroll
    for (int i = 0; i <= NPW; ++i) offv[i] = off[wbase + i];

    int2 rec0[NPW];                    // first-block records, all nodes
#pragma unroll
    for (int i = 0; i < NPW; ++i) {
        int2 r = make_int2(N_NODES, 0);
        if (c < offv[i + 1] - offv[i]) r = edges[offv[i] + c];
        rec0[i] = r;
    }

    int ldP[2][4], eyP[2][4];          // ping-pong chunk-0 gather sets
#define ISSUE(P, I)                                                              \
    {                                                                            \
        _Pragma("unroll")                                                        \
        for (int j = 0; j < 4; ++j) {                                            \
            int sx = __builtin_amdgcn_ds_bpermute(asb + (j << 4), rec0[I].x);    \
            eyP[P][j] = __builtin_amdgcn_ds_bpermute(asb + (j << 4), rec0[I].y); \
            ldP[P][j] = *(const int*)(hin8 + ((sx << 6) + dwoff));               \
        }                                                                        \
    }
#define CONSUME(LD, EA)                                                          \
    {                                                                            \
        h2vec av = __builtin_bit_cast(h2vec, EA);                                \
        float q0 = __builtin_amdgcn_fdot2(av, weq[0], beq[0], false);            \
        float q1 = __builtin_amdgcn_fdot2(av, weq[1], beq[1], false);            \
        float q2 = __builtin_amdgcn_fdot2(av, weq[2], beq[2], false);            \
        float q3 = __builtin_amdgcn_fdot2(av, weq[3], beq[3], false);            \
        acc0 += fmaxf(__builtin_amdgcn_cvt_f32_fp8(LD, 0) + q0, 0.f);            \
        acc1 += fmaxf(__builtin_amdgcn_cvt_f32_fp8(LD, 1) + q1, 0.f);            \
        acc2 += fmaxf(__builtin_amdgcn_cvt_f32_fp8(LD, 2) + q2, 0.f);            \
        acc3 += fmaxf(__builtin_amdgcn_cvt_f32_fp8(LD, 3) + q3, 0.f);            \
    }

    ISSUE(0, 0)
#pragma unroll
    for (int nn = 0; nn < NPW; ++nn) {
        const int p = nn & 1;
        if (nn + 1 < NPW) ISSUE(p ^ 1, nn + 1)   // overlap next node's chunk-0 gathers
        const int n = wbase + nn;
        const int rs = offv[nn], re = offv[nn + 1];
        const int cnt0 = min(64, re - rs);
        // conditional early chunk-1 (slots 16-31): wave-uniform branch, ~47% of nodes.
        int ldQ[4], eyQ[4];
        const bool hasQ = cnt0 > 16;
        if (hasQ) {
#pragma unroll
            for (int j = 0; j < 4; ++j) {
                const int ab = 64 + asb + (j << 4);
                int sx = __builtin_amdgcn_ds_bpermute(ab, rec0[nn].x);
                eyQ[j] = __builtin_amdgcn_ds_bpermute(ab, rec0[nn].y);
                ldQ[j] = *(const int*)(hin8 + ((sx << 6) + dwoff));
            }
        }
        const float hc = __half2float(hin[(size_t)n * 64 + c]);
        float acc0 = 0.f, acc1 = 0.f, acc2 = 0.f, acc3 = 0.f;
        CONSUME(ldP[p][0], eyP[p][0])
        CONSUME(ldP[p][1], eyP[p][1])
        CONSUME(ldP[p][2], eyP[p][2])
        CONSUME(ldP[p][3], eyP[p][3])
        if (hasQ) {
            CONSUME(ldQ[0], eyQ[0])
            CONSUME(ldQ[1], eyQ[1])
            CONSUME(ldQ[2], eyQ[2])
            CONSUME(ldQ[3], eyQ[3])
        }
        // remainder chunks of first block (deg > 32, ~0.01% of nodes)
        for (int j0 = 32; j0 < cnt0; j0 += 16) {
            const int ab = (j0 << 2) + asb;
            int s0 = __builtin_amdgcn_ds_bpermute(ab,      rec0[nn].x);
            int s1 = __builtin_amdgcn_ds_bpermute(ab + 16, rec0[nn].x);
            int s2 = __builtin_amdgcn_ds_bpermute(ab + 32, rec0[nn].x);
            int s3 = __builtin_amdgcn_ds_bpermute(ab + 48, rec0[nn].x);
            int e0 = __builtin_amdgcn_ds_bpermute(ab,      rec0[nn].y);
            int e1 = __builtin_amdgcn_ds_bpermute(ab + 16, rec0[nn].y);
            int e2 = __builtin_amdgcn_ds_bpermute(ab + 32, rec0[nn].y);
            int e3 = __builtin_amdgcn_ds_bpermute(ab + 48, rec0[nn].y);
            int ld0 = *(const int*)(hin8 + ((s0 << 6) + dwoff));
            int ld1 = *(const int*)(hin8 + ((s1 << 6) + dwoff));
            int ld2 = *(const int*)(hin8 + ((s2 << 6) + dwoff));
            int ld3 = *(const int*)(hin8 + ((s3 << 6) + dwoff));
            CONSUME(ld0, e0)
            CONSUME(ld1, e1)
            CONSUME(ld2, e2)
            CONSUME(ld3, e3)
        }
        // deg > 64 tail blocks (rare) — verbatim r3
        for (int base = rs + 64; base < re; base += 64) {
            const int cnt = min(64, re - base);
            int2 rec = make_int2(N_NODES, 0);
            if (c < cnt) rec = edges[base + c];
            for (int j0 = 0; j0 < cnt; j0 += 16) {
                const int ab = (j0 << 2) + asb;
                int s0 = __builtin_amdgcn_ds_bpermute(ab,      rec.x);
                int s1 = __builtin_amdgcn_ds_bpermute(ab + 16, rec.x);
                int s2 = __builtin_amdgcn_ds_bpermute(ab + 32, rec.x);
                int s3 = __builtin_amdgcn_ds_bpermute(ab + 48, rec.x);
                int e0 = __builtin_amdgcn_ds_bpermute(ab,      rec.y);
                int e1 = __builtin_amdgcn_ds_bpermute(ab + 16, rec.y);
                int e2 = __builtin_amdgcn_ds_bpermute(ab + 32, rec.y);
                int e3 = __builtin_amdgcn_ds_bpermute(ab + 48, rec.y);
                int ld0 = *(const int*)(hin8 + ((s0 << 6) + dwoff));
                int ld1 = *(const int*)(hin8 + ((s1 << 6) + dwoff));
                int ld2 = *(const int*)(hin8 + ((s2 << 6) + dwoff));
                int ld3 = *(const int*)(hin8 + ((s3 << 6) + dwoff));
                CONSUME(ld0, e0)
                CONSUME(ld1, e1)
                CONSUME(ld2, e2)
                CONSUME(ld3, e3)
            }
        }
        // fold 4 edge-slot groups (lane bits 4,5)
        acc0 += __shfl_xor(acc0, 16); acc1 += __shfl_xor(acc1, 16);
        acc2 += __shfl_xor(acc2, 16); acc3 += __shfl_xor(acc3, 16);
        acc0 += __shfl_xor(acc0, 32); acc1 += __shfl_xor(acc1, 32);
        acc2 += __shfl_xor(acc2, 32); acc3 += __shfl_xor(acc3, 32);
        h4vec aq = {(_Float16)acc0, (_Float16)acc1, (_Float16)acc2, (_Float16)acc3};
        *(h4vec*)&uL[w][q4] = aq;            // duplicate writers, same value
        float u = hc + (float)uL[w][c];      // per-channel center add
        uL[w][c] = (_Float16)u;
        float z = 0.f;
        const h4vec* u4p = (const h4vec*)uL[w];
        const h4vec* wt4p = (const h4vec*)&WtL[c][0];
#pragma unroll
        for (int k4 = 0; k4 < 16; ++k4) {
            h4vec uu = u4p[k4];
            h4vec ww = wt4p[k4];
            h2vec ul = __builtin_shufflevector(uu, uu, 0, 1);
            h2vec uh = __builtin_shufflevector(uu, uu, 2, 3);
            h2vec wl = __builtin_shufflevector(ww, ww, 0, 1);
            h2vec wh = __builtin_shufflevector(ww, ww, 2, 3);
            z = __builtin_amdgcn_fdot2(ul, wl, z, false);
            z = __builtin_amdgcn_fdot2(uh, wh, z, false);
        }
        float v = fmaxf(fmaf(z, sj, cj), 0.f) + hc;
        hout[(size_t)n * 64 + c] = __float2half(v);
        hout8[(size_t)n * 64 + c] = f32_to_fp8(v);
    }
#undef CONSUME
#undef ISSUE
}

// ---------------- Pool (mean+max per graph) + classifier ----------------
__global__ __launch_bounds__(256) void k_pool(
    const __half* __restrict__ h, const int* __restrict__ batch,
    const float* __restrict__ Wc1, const float* __restrict__ bc1,
    const float* __restrict__ Wc2, const float* __restrict__ bc2,
    float* __restrict__ out) {
    __shared__ float psum[4][64];
    __shared__ float pmax[4][64];
    __shared__ float pool[128];
    __shared__ float hid[64];
    const int t = threadIdx.x, w = t >> 6, c = t & 63;
    const int g = blockIdx.x;
    int lo = 0, hi = N_NODES;
    while (lo < hi) { int mid = (lo + hi) >> 1; if (batch[mid] < g) lo = mid + 1; else hi = mid; }
    int start = lo;
    hi = N_NODES;
    while (lo < hi) { int mid = (lo + hi) >> 1; if (batch[mid] < g + 1) lo = mid + 1; else hi = mid; }
    int end = lo;

    float s = 0.f, m = -3.4e38f;
    for (int i = start + w; i < end; i += 4) {
        float v = __half2float(h[(size_t)i * 64 + c]);
        s += v;
        m = fmaxf(m, v);
    }
    psum[w][c] = s;
    pmax[w][c] = m;
    __syncthreads();
    if (w == 0) {
        float ss = psum[0][c] + psum[1][c] + psum[2][c] + psum[3][c];
        float mm = fmaxf(fmaxf(pmax[0][c], pmax[1][c]), fmaxf(pmax[2][c], pmax[3][c]));
        int cnt = end - start;
        pool[c] = ss / fmaxf((float)cnt, 1.f);
        pool[64 + c] = (cnt > 0) ? mm : 0.f;
    }
    __syncthreads();
    if (t < 64) {
        float z = bc1[t];
#pragma unroll 8
        for (int k = 0; k < 128; ++k) z = fmaf(pool[k], Wc1[k * 64 + t], z);
        hid[t] = fmaxf(z, 0.f);
    }
    __syncthreads();
    if (t < N_CLS) {
        float z = bc2[t];
#pragma unroll
        for (int k = 0; k < 64; ++k) z = fmaf(hid[k], Wc2[k * N_CLS + t], z);
        out[g * N_CLS + t] = z;
    }
}

extern "C" void kernel_launch(void* const* d_in, const int* in_sizes, int n_in,
                              void* d_out, int out_size, void* d_ws, size_t ws_size,
                              hipStream_t stream) {
    const float* x     = (const float*)d_in[0];
    const int*   ei    = (const int*)d_in[1];
    const float* ea    = (const float*)d_in[2];
    const int*   batch = (const int*)d_in[3];
    const float* We1 = (const float*)d_in[4],  *be1 = (const float*)d_in[5];
    const float* We2 = (const float*)d_in[6],  *be2 = (const float*)d_in[7];
    const float* We3 = (const float*)d_in[8],  *be3 = (const float*)d_in[9];
    const float* W1 = (const float*)d_in[10], *b1 = (const float*)d_in[11];
    const float* g1 = (const float*)d_in[12], *bt1 = (const float*)d_in[13];
    const float* rm1 = (const float*)d_in[14], *rv1 = (const float*)d_in[15];
    const float* W2 = (const float*)d_in[16], *b2 = (const float*)d_in[17];
    const float* g2 = (const float*)d_in[18], *bt2 = (const float*)d_in[19];
    const float* rm2 = (const float*)d_in[20], *rv2 = (const float*)d_in[21];
    const float* W3 = (const float*)d_in[22], *b3 = (const float*)d_in[23];
    const float* g3 = (const float*)d_in[24], *bt3 = (const float*)d_in[25];
    const float* rm3 = (const float*)d_in[26], *rv3 = (const float*)d_in[27];
    const float* Wr = (const float*)d_in[28], *br = (const float*)d_in[29];
    const float* Wc1 = (const float*)d_in[30], *bc1 = (const float*)d_in[31];
    const float* Wc2 = (const float*)d_in[32], *bc2 = (const float*)d_in[33];

    int* off    = (int*)d_ws;                   // N+4
    int* gcount = off + (N_NODES + 4);          // 1024 (NB=1000, zero-padded)
    int* bbase  = gcount + 1024;                // 1024
    int2* edges = (int2*)(bbase + 1024);        // E * 8B packed records
    int2* stage = edges + E_EDGES;              // NB*BCAP * 8B fixed bucket regions
    __half* hA  = (__half*)(stage + (size_t)NB * BCAP);  // N*64 fp16
    __half* hB  = hA + (size_t)N_NODES * 64;    // N*64 fp16
    unsigned char* hA8 = (unsigned char*)(hB + (size_t)N_NODES * 64);  // (N+1)*64 fp8
    unsigned char* hB8 = hA8 + (size_t)(N_NODES + 1) * 64;             // (N+1)*64 fp8
    __half* x16 = (__half*)(hB8 + (size_t)(N_NODES + 1) * 64);         // (N+1)*16 fp16

    hipMemsetAsync(gcount, 0, 1024 * sizeof(int), stream);
    // sentinel fp8 rows: 0xFE = -448 e4m3fn -> ReLU kills tail-edge messages
    hipMemsetAsync(hA8 + (size_t)N_NODES * 64, 0xFE, 64, stream);
    hipMemsetAsync(hB8 + (size_t)N_NODES * 64, 0xFE, 64, stream);

    const int* src = ei;
    const int* dst = ei + E_EDGES;

    k_pack_x<<<((N_NODES + 1) * 16 + 255) / 256, 256, 0, stream>>>(x, x16);
    k_bin<<<E_EDGES / TILE, 256, 0, stream>>>(src, dst, (const float2*)ea, gcount, stage);
    k_bscan<<<1, 256, 0, stream>>>(gcount, bbase, off);
    k_final<<<NB, 256, 0, stream>>>(gcount, bbase, stage, off, edges);

    k_gine12<<<N_NODES / (4 * NPW12), 256, 0, stream>>>(x, x16, hA, hA8, off, edges,
                                                        We1, be1, W1, b1, g1, bt1, rm1, rv1, Wr, br);
    const int g64_blocks = N_NODES / (4 * NPW);  // 4000
    k_gine64<<<g64_blocks, 256, 0, stream>>>(hA, hA8, hB, hB8, off, edges,
                                             We2, be2, W2, b2, g2, bt2, rm2, rv2);
    k_gine64<<<g64_blocks, 256, 0, stream>>>(hB, hB8, hA, hA8, off, edges,
                                             We3, be3, W3, b3, g3, bt3, rm3, rv3);
    k_pool<<<G_GRAPHS, 256, 0, stream>>>(hA, batch, Wc1, bc1, Wc2, bc2, (float*)d_out);
}

// Round 16
// 422.536 us; speedup vs baseline: 1.0892x; 1.0892x over previous
//
#include <hip/hip_runtime.h>
#include <hip/hip_bf16.h>
#include <hip/hip_fp16.h>

#define N_NODES 128000
#define E_EDGES 2048000
#define G_GRAPHS 512
#define D_IN 12
#define D_H 64
#define N_CLS 10
#define BN_EPS 1e-5f
#define NB 1000        // buckets = dst >> 7 (128-node ranges)
#define BCAP 2560      // fixed records per bucket region
#define TILE 8192      // edges per k_bin block (250 blocks; smaller tiles shrink write runs -> regress)
#define NPW 8          // nodes per wave in gine64
#define NPW12 4        // nodes per wave in gine12

typedef _Float16 h2vec __attribute__((ext_vector_type(2)));
typedef _Float16 h4vec __attribute__((ext_vector_type(4)));

__device__ __forceinline__ unsigned char f32_to_fp8(float v) {
    return (unsigned char)(__builtin_amdgcn_cvt_pk_fp8_f32(v, v, 0, false) & 0xff);
}

// ---------------- CSR build: bucket counting-sort ----------------
// Sort-then-write (r8) at TILE=8192. 250 blocks on 256 CUs = 1 block/CU always, so
// r16: 512 threads/block (8 waves) to double wave-level MLP — k_bin profiled at
// VALUBusy 2.6% (pure latency/scatter stall), waves are the only available lever.

__global__ __launch_bounds__(512) void k_bin(const int* __restrict__ src, const int* __restrict__ dst,
                                             const float2* __restrict__ attr, int* __restrict__ gcount,
                                             int2* __restrict__ stage) {
    __shared__ int hist[NB];
    __shared__ int base_s[NB];
    __shared__ int bscan[NB];                // block-local sorted start per bucket
    __shared__ int rk[TILE];                 // packed b(10)<<20 | dstLow(7)<<13 | rank(13)
    __shared__ unsigned short sorted[TILE];  // sorted position -> edge idx
    __shared__ int psum[512];
    const int t = threadIdx.x;
    const int e0 = blockIdx.x * TILE;
    for (int i = t; i < NB; i += 512) hist[i] = 0;
    __syncthreads();
    for (int i = t; i < TILE; i += 512) {
        int d = dst[e0 + i];
        int b = d >> 7;
        int r = atomicAdd(&hist[b], 1);
        rk[i] = (b << 20) | ((d & 127) << 13) | r;
    }
    __syncthreads();
    // block-local exclusive scan over NB buckets (each thread owns 2)
    int h0 = (t * 2     < NB) ? hist[t * 2]     : 0;
    int h1 = (t * 2 + 1 < NB) ? hist[t * 2 + 1] : 0;
    int s = h0 + h1;
    psum[t] = s;
    __syncthreads();
    for (int off = 1; off < 512; off <<= 1) {
        int x = 0;
        if (t >= off) x = psum[t - off];
        __syncthreads();
        psum[t] += x;
        __syncthreads();
    }
    int base = psum[t] - s;  // exclusive
    if (t * 2     < NB) bscan[t * 2]     = base;
    if (t * 2 + 1 < NB) bscan[t * 2 + 1] = base + h0;
    for (int i = t; i < NB; i += 512) {
        int cb = hist[i];
        base_s[i] = i * BCAP + ((cb > 0) ? atomicAdd(&gcount[i], cb) : 0);
    }
    __syncthreads();
    // inverse permutation: sorted position -> edge index
    for (int i = t; i < TILE; i += 512) {
        int pr = rk[i];
        int b = pr >> 20, r = pr & 8191;
        sorted[bscan[b] + r] = (unsigned short)i;
    }
    __syncthreads();
    // write stage in sorted order: contiguous runs per bucket
    for (int p = t; p < TILE; p += 512) {
        int i = sorted[p];
        int pr = rk[i];
        int b = pr >> 20, dl = (pr >> 13) & 127, r = pr & 8191;
        float2 a = attr[e0 + i];
        __half2 h2 = __floats2half2_rn(a.x, a.y);
        stage[base_s[b] + r] = make_int2(src[e0 + i] | (dl << 17), *(int*)&h2);
    }
}

__global__ __launch_bounds__(256) void k_bscan(const int* __restrict__ gcount, int* __restrict__ bbase,
                                               int* __restrict__ offsets) {
    __shared__ int sm[256];
    const int t = threadIdx.x;
    int c0 = gcount[t * 4], c1 = gcount[t * 4 + 1], c2 = gcount[t * 4 + 2], c3 = gcount[t * 4 + 3];
    int s = c0 + c1 + c2 + c3;
    sm[t] = s;
    __syncthreads();
    for (int off = 1; off < 256; off <<= 1) {
        int x = 0;
        if (t >= off) x = sm[t - off];
        __syncthreads();
        sm[t] += x;
        __syncthreads();
    }
    int base = sm[t] - s;  // exclusive
    if (t * 4 < NB)     bbase[t * 4]     = base;
    if (t * 4 + 1 < NB) bbase[t * 4 + 1] = base + c0;
    if (t * 4 + 2 < NB) bbase[t * 4 + 2] = base + c0 + c1;
    if (t * 4 + 3 < NB) bbase[t * 4 + 3] = base + c0 + c1 + c2;
    if (t == 255) offsets[N_NODES] = sm[255];
}

__global__ __launch_bounds__(256) void k_final(const int* __restrict__ gcount, const int* __restrict__ bbase,
                                               const int2* __restrict__ stage,
                                               int* __restrict__ offsets, int2* __restrict__ edges) {
    __shared__ int2 recs[BCAP];   // 20.5 KB
    __shared__ int cnt[128];
    __shared__ int incl[128];
    const int b = blockIdx.x, t = threadIdx.x;
    const int count = gcount[b];
    const int base = bbase[b];
    if (t < 128) cnt[t] = 0;
    __syncthreads();
    for (int i = t; i < count; i += 256) {
        int2 r = stage[b * BCAP + i];
        recs[i] = r;
        atomicAdd(&cnt[(r.x >> 17) & 127], 1);
    }
    __syncthreads();
    if (t < 128) incl[t] = cnt[t];
    __syncthreads();
    for (int off = 1; off < 128; off <<= 1) {   // parallel Hillis-Steele over 128
        int x = 0;
        if (t >= off && t < 128) x = incl[t - off];
        __syncthreads();
        if (t < 128) incl[t] += x;
        __syncthreads();
    }
    if (t < 128) {
        int ex = incl[t] - cnt[t];
        offsets[b * 128 + t] = base + ex;
        cnt[t] = ex;   // becomes the placement cursor
    }
    __syncthreads();
    for (int i = t; i < count; i += 256) {
        int2 r = recs[i];
        int dl = (r.x >> 17) & 127;
        int p = atomicAdd(&cnt[dl], 1);
        edges[base + p] = make_int2(r.x & 0x1FFFF, r.y);
    }
}

// pack x [N,12] fp32 -> [N+1,16] fp16 (channels 12..15 = 0); row N = sentinel -3e4
__global__ __launch_bounds__(256) void k_pack_x(const float* __restrict__ x, __half* __restrict__ x16) {
    int idx = blockIdx.x * 256 + threadIdx.x;
    if (idx >= (N_NODES + 1) * 16) return;
    int n = idx >> 4, ch = idx & 15;
    float v = (n == N_NODES) ? -30000.f : ((ch < D_IN) ? x[n * D_IN + ch] : 0.f);
    x16[idx] = __float2half(v);
}

// ---------------- Layer 1 (12-dim input, 64-dim output; fp16+fp8 out) ----------------
// 8 edges per dword load (32B row = 8 dwords); lane l = edge-slot (l>>3), channel-pair (l&7).
// r3-proven load structure (FROZEN — restructuring failed 3x: r4/r5/r11).
__global__ __launch_bounds__(256) void k_gine12(
    const float* __restrict__ x, const __half* __restrict__ x16,
    __half* __restrict__ hout, unsigned char* __restrict__ hout8,
    const int* __restrict__ off, const int2* __restrict__ edges,
    const float* __restrict__ We1, const float* __restrict__ be1,
    const float* __restrict__ W1, const float* __restrict__ b1,
    const float* __restrict__ g1, const float* __restrict__ bt1,
    const float* __restrict__ rm1, const float* __restrict__ rv1,
    const float* __restrict__ Wr, const float* __restrict__ br) {
    __shared__ float W1lds[D_IN * 64];
    __shared__ float Wrlds[D_IN * 64];
    __shared__ float uacc[4][16];
    __shared__ float u_lds[4][D_IN];
    __shared__ float x_lds[4][D_IN];
    const int t = threadIdx.x, w = t >> 6, c = t & 63;
    const int asb = (c >> 3) << 2;    // bpermute base: edge-slot
    const int dwoff = (c & 7) << 2;   // dword byte offset within 32B row
    const int ch0 = (c & 7) << 1;     // this lane's channel pair
    for (int i = t; i < D_IN * 64; i += 256) {
        W1lds[i] = W1[i];
        Wrlds[i] = Wr[i];
    }
    h2vec wp0 = {(_Float16)0.f, (_Float16)0.f}, wp1 = wp0;
    float bp0 = 0.f, bp1 = 0.f;
    if (ch0 < D_IN)     { wp0[0] = (_Float16)We1[ch0];     wp0[1] = (_Float16)We1[D_IN + ch0];     bp0 = be1[ch0]; }
    if (ch0 + 1 < D_IN) { wp1[0] = (_Float16)We1[ch0 + 1]; wp1[1] = (_Float16)We1[D_IN + ch0 + 1]; bp1 = be1[ch0 + 1]; }
    const float sj = g1[c] * rsqrtf(rv1[c] + BN_EPS);
    const float cj = (b1[c] - rm1[c]) * sj + bt1[c];
    const float brj = br[c];
    __syncthreads();

    // XCD swizzle: 8000 blocks = 8 XCDs x 1000; same-XCD blocks -> contiguous nodes
    const int swz = (blockIdx.x & 7) * 1000 + (blockIdx.x >> 3);
    const int wbase = (swz * 4 + w) * NPW12;
    for (int nn = 0; nn < NPW12; ++nn) {
        const int n = wbase + nn;
        const int rs = off[n], re = off[n + 1];
        float a0 = 0.f, a1 = 0.f;
        for (int base = rs; base < re; base += 64) {
            const int cnt = min(64, re - base);
            int2 rec = make_int2(N_NODES, 0);
            if (c < cnt) rec = edges[base + c];
            for (int j0 = 0; j0 < cnt; j0 += 16) {
                const int ab = (j0 << 2) + asb;
                int s0 = __builtin_amdgcn_ds_bpermute(ab,      rec.x);
                int s1 = __builtin_amdgcn_ds_bpermute(ab + 32, rec.x);
                int e0 = __builtin_amdgcn_ds_bpermute(ab,      rec.y);
                int e1 = __builtin_amdgcn_ds_bpermute(ab + 32, rec.y);
                int ld0 = *(const int*)((const char*)x16 + ((s0 << 5) + dwoff));
                int ld1 = *(const int*)((const char*)x16 + ((s1 << 5) + dwoff));
                {
                    h2vec hv = __builtin_bit_cast(h2vec, ld0);
                    h2vec av = __builtin_bit_cast(h2vec, e0);
                    float q0 = __builtin_amdgcn_fdot2(av, wp0, bp0, false);
                    float q1 = __builtin_amdgcn_fdot2(av, wp1, bp1, false);
                    a0 += fmaxf((float)hv[0] + q0, 0.f);
                    a1 += fmaxf((float)hv[1] + q1, 0.f);
                }
                {
                    h2vec hv = __builtin_bit_cast(h2vec, ld1);
                    h2vec av = __builtin_bit_cast(h2vec, e1);
                    float q0 = __builtin_amdgcn_fdot2(av, wp0, bp0, false);
                    float q1 = __builtin_amdgcn_fdot2(av, wp1, bp1, false);
                    a0 += fmaxf((float)hv[0] + q0, 0.f);
                    a1 += fmaxf((float)hv[1] + q1, 0.f);
                }
            }
        }
        // fold 8 edge-slot groups (lane bits 3,4,5)
        a0 += __shfl_xor(a0, 8);  a1 += __shfl_xor(a1, 8);
        a0 += __shfl_xor(a0, 16); a1 += __shfl_xor(a1, 16);
        a0 += __shfl_xor(a0, 32); a1 += __shfl_xor(a1, 32);
        uacc[w][ch0] = a0;        // duplicate writers, same value
        uacc[w][ch0 + 1] = a1;
        if (c < D_IN) {
            float xc = x[(size_t)n * D_IN + c];
            x_lds[w][c] = xc;
            u_lds[w][c] = xc + uacc[w][c];
        }
        float z = 0.f, r = 0.f;
#pragma unroll
        for (int k = 0; k < D_IN; ++k) {
            z = fmaf(u_lds[w][k], W1lds[k * 64 + c], z);
            r = fmaf(x_lds[w][k], Wrlds[k * 64 + c], r);
        }
        float v = fmaxf(fmaf(z, sj, cj), 0.f) + r + brj;
        hout[(size_t)n * 64 + c] = __float2half(v);
        hout8[(size_t)n * 64 + c] = f32_to_fp8(v);
    }
}

// ---------------- Layers 2/3: fp8 gather, depth-1 pipeline + conditional early chunk-1 ----------------
// Lane l = edge-slot (l>>4), channel-quad (l&15). Loaded dword IS the accumulation layout.
// Chunk-0 (slots 0-15) prefetched one node ahead (r10 ping-pong). Chunk-1 (slots 16-31)
// issued EARLY only when deg>16 (wave-uniform branch) so its gather latency hides under
// chunk-0's consume; zero added work for deg<=16 nodes. Sentinel-killed tails (r7-verified).
__global__ __launch_bounds__(256) void k_gine64(
    const __half* __restrict__ hin, const unsigned char* __restrict__ hin8,
    __half* __restrict__ hout, unsigned char* __restrict__ hout8,
    const int* __restrict__ off, const int2* __restrict__ edges,
    const float* __restrict__ We, const float* __restrict__ be,
    const float* __restrict__ W, const float* __restrict__ b,
    const float* __restrict__ g, const float* __restrict__ bt,
    const float* __restrict__ rm, const float* __restrict__ rv) {
    __shared__ _Float16 WtL[64][68];   // transposed W, fp16
    __shared__ _Float16 uL[4][64];
    const int t = threadIdx.x, w = t >> 6, c = t & 63;
    for (int i = t; i < 4096; i += 256) {
        int k = i >> 6, cc = i & 63;
        WtL[cc][k] = (_Float16)W[i];   // W[k*64+cc]
    }
    const int asb   = (c >> 4) << 2;   // bpermute base: edge-slot
    const int dwoff = (c & 15) << 2;   // dword byte offset within 64B row
    const int q4    = (c & 15) << 2;   // base channel of this lane's quad
    h2vec weq[4];
    float beq[4];
#pragma unroll
    for (int j = 0; j < 4; ++j) {
        weq[j][0] = (_Float16)We[q4 + j];
        weq[j][1] = (_Float16)We[64 + q4 + j];
        beq[j] = be[q4 + j];
    }
    const float sj = g[c] * rsqrtf(rv[c] + BN_EPS);
    const float cj = (b[c] - rm[c]) * sj + bt[c];
    __syncthreads();

    // XCD swizzle: 4000 blocks = 8 XCDs x 500; same-XCD blocks -> contiguous nodes
    const int swz = (blockIdx.x & 7) * 500 + (blockIdx.x >> 3);
    const int wbase = (swz * 4 + w) * NPW;

    int offv[NPW + 1];
#pragma unroll
    for (int i = 0; i <= NPW; ++i) offv[i] = off[wbase + i];

    int2 rec0[NPW];                    // first-block records, all nodes
#pragma unroll
    for (int i = 0; i < NPW; ++i) {
        int2 r = make_int2(N_NODES, 0);
        if (c < offv[i + 1] - offv[i]) r = edges[offv[i] + c];
        rec0[i] = r;
    }

    int ldP[2][4], eyP[2][4];          // ping-pong chunk-0 gather sets
#define ISSUE(P, I)                                                              \
    {                                                                            \
        _Pragma("unroll")                                                        \
        for (int j = 0; j < 4; ++j) {                                            \
            int sx = __builtin_amdgcn_ds_bpermute(asb + (j << 4), rec0[I].x);    \
            eyP[P][j] = __builtin_amdgcn_ds_bpermute(asb + (j << 4), rec0[I].y); \
            ldP[P][j] = *(const int*)(hin8 + ((sx << 6) + dwoff));               \
        }                                                                        \
    }
#define CONSUME(LD, EA)                                                          \
    {                                                                            \
        h2vec av = __builtin_bit_cast(h2vec, EA);                                \
        float q0 = __builtin_amdgcn_fdot2(av, weq[0], beq[0], false);            \
        float q1 = __builtin_amdgcn_fdot2(av, weq[1], beq[1], false);            \
        float q2 = __builtin_amdgcn_fdot2(av, weq[2], beq[2], false);            \
        float q3 = __builtin_amdgcn_fdot2(av, weq[3], beq[3], false);            \
        acc0 += fmaxf(__builtin_amdgcn_cvt_f32_fp8(LD, 0) + q0, 0.f);            \
        acc1 += fmaxf(__builtin_amdgcn_cvt_f32_fp8(LD, 1) + q1, 0.f);            \
        acc2 += fmaxf(__builtin_amdgcn_cvt_f32_fp8(LD, 2) + q2, 0.f);            \
        acc3 += fmaxf(__builtin_amdgcn_cvt_f32_fp8(LD, 3) + q3, 0.f);            \
    }

    ISSUE(0, 0)
#pragma unroll
    for (int nn = 0; nn < NPW; ++nn) {
        const int p = nn & 1;
        if (nn + 1 < NPW) ISSUE(p ^ 1, nn + 1)   // overlap next node's chunk-0 gathers
        const int n = wbase + nn;
        const int rs = offv[nn], re = offv[nn + 1];
        const int cnt0 = min(64, re - rs);
        // conditional early chunk-1 (slots 16-31): wave-uniform branch, ~47% of nodes.
        int ldQ[4], eyQ[4];
        const bool hasQ = cnt0 > 16;
        if (hasQ) {
#pragma unroll
            for (int j = 0; j < 4; ++j) {
                const int ab = 64 + asb + (j << 4);
                int sx = __builtin_amdgcn_ds_bpermute(ab, rec0[nn].x);
                eyQ[j] = __builtin_amdgcn_ds_bpermute(ab, rec0[nn].y);
                ldQ[j] = *(const int*)(hin8 + ((sx << 6) + dwoff));
            }
        }
        const float hc = __half2float(hin[(size_t)n * 64 + c]);
        float acc0 = 0.f, acc1 = 0.f, acc2 = 0.f, acc3 = 0.f;
        CONSUME(ldP[p][0], eyP[p][0])
        CONSUME(ldP[p][1], eyP[p][1])
        CONSUME(ldP[p][2], eyP[p][2])
        CONSUME(ldP[p][3], eyP[p][3])
        if (hasQ) {
            CONSUME(ldQ[0], eyQ[0])
            CONSUME(ldQ[1], eyQ[1])
            CONSUME(ldQ[2], eyQ[2])
            CONSUME(ldQ[3], eyQ[3])
        }
        // remainder chunks of first block (deg > 32, ~0.01% of nodes)
        for (int j0 = 32; j0 < cnt0; j0 += 16) {
            const int ab = (j0 << 2) + asb;
            int s0 = __builtin_amdgcn_ds_bpermute(ab,      rec0[nn].x);
            int s1 = __builtin_amdgcn_ds_bpermute(ab + 16, rec0[nn].x);
            int s2 = __builtin_amdgcn_ds_bpermute(ab + 32, rec0[nn].x);
            int s3 = __builtin_amdgcn_ds_bpermute(ab + 48, rec0[nn].x);
            int e0 = __builtin_amdgcn_ds_bpermute(ab,      rec0[nn].y);
            int e1 = __builtin_amdgcn_ds_bpermute(ab + 16, rec0[nn].y);
            int e2 = __builtin_amdgcn_ds_bpermute(ab + 32, rec0[nn].y);
            int e3 = __builtin_amdgcn_ds_bpermute(ab + 48, rec0[nn].y);
            int ld0 = *(const int*)(hin8 + ((s0 << 6) + dwoff));
            int ld1 = *(const int*)(hin8 + ((s1 << 6) + dwoff));
            int ld2 = *(const int*)(hin8 + ((s2 << 6) + dwoff));
            int ld3 = *(const int*)(hin8 + ((s3 << 6) + dwoff));
            CONSUME(ld0, e0)
            CONSUME(ld1, e1)
            CONSUME(ld2, e2)
            CONSUME(ld3, e3)
        }
        // deg > 64 tail blocks (rare) — verbatim r3
        for (int base = rs + 64; base < re; base += 64) {
            const int cnt = min(64, re - base);
            int2 rec = make_int2(N_NODES, 0);
            if (c < cnt) rec = edges[base + c];
            for (int j0 = 0; j0 < cnt; j0 += 16) {
                const int ab = (j0 << 2) + asb;
                int s0 = __builtin_amdgcn_ds_bpermute(ab,      rec.x);
                int s1 = __builtin_amdgcn_ds_bpermute(ab + 16, rec.x);
                int s2 = __builtin_amdgcn_ds_bpermute(ab + 32, rec.x);
                int s3 = __builtin_amdgcn_ds_bpermute(ab + 48, rec.x);
                int e0 = __builtin_amdgcn_ds_bpermute(ab,      rec.y);
                int e1 = __builtin_amdgcn_ds_bpermute(ab + 16, rec.y);
                int e2 = __builtin_amdgcn_ds_bpermute(ab + 32, rec.y);
                int e3 = __builtin_amdgcn_ds_bpermute(ab + 48, rec.y);
                int ld0 = *(const int*)(hin8 + ((s0 << 6) + dwoff));
                int ld1 = *(const int*)(hin8 + ((s1 << 6) + dwoff));
                int ld2 = *(const int*)(hin8 + ((s2 << 6) + dwoff));
                int ld3 = *(const int*)(hin8 + ((s3 << 6) + dwoff));
                CONSUME(ld0, e0)
                CONSUME(ld1, e1)
                CONSUME(ld2, e2)
                CONSUME(ld3, e3)
            }
        }
        // fold 4 edge-slot groups (lane bits 4,5)
        acc0 += __shfl_xor(acc0, 16); acc1 += __shfl_xor(acc1, 16);
        acc2 += __shfl_xor(acc2, 16); acc3 += __shfl_xor(acc3, 16);
        acc0 += __shfl_xor(acc0, 32); acc1 += __shfl_xor(acc1, 32);
        acc2 += __shfl_xor(acc2, 32); acc3 += __shfl_xor(acc3, 32);
        h4vec aq = {(_Float16)acc0, (_Float16)acc1, (_Float16)acc2, (_Float16)acc3};
        *(h4vec*)&uL[w][q4] = aq;            // duplicate writers, same value
        float u = hc + (float)uL[w][c];      // per-channel center add
        uL[w][c] = (_Float16)u;
        float z = 0.f;
        const h4vec* u4p = (const h4vec*)uL[w];
        const h4vec* wt4p = (const h4vec*)&WtL[c][0];
#pragma unroll
        for (int k4 = 0; k4 < 16; ++k4) {
            h4vec uu = u4p[k4];
            h4vec ww = wt4p[k4];
            h2vec ul = __builtin_shufflevector(uu, uu, 0, 1);
            h2vec uh = __builtin_shufflevector(uu, uu, 2, 3);
            h2vec wl = __builtin_shufflevector(ww, ww, 0, 1);
            h2vec wh = __builtin_shufflevector(ww, ww, 2, 3);
            z = __builtin_amdgcn_fdot2(ul, wl, z, false);
            z = __builtin_amdgcn_fdot2(uh, wh, z, false);
        }
        float v = fmaxf(fmaf(z, sj, cj), 0.f) + hc;
        hout[(size_t)n * 64 + c] = __float2half(v);
        hout8[(size_t)n * 64 + c] = f32_to_fp8(v);
    }
#undef CONSUME
#undef ISSUE
}

// ---------------- Pool (mean+max per graph) + classifier ----------------
__global__ __launch_bounds__(256) void k_pool(
    const __half* __restrict__ h, const int* __restrict__ batch,
    const float* __restrict__ Wc1, const float* __restrict__ bc1,
    const float* __restrict__ Wc2, const float* __restrict__ bc2,
    float* __restrict__ out) {
    __shared__ float psum[4][64];
    __shared__ float pmax[4][64];
    __shared__ float pool[128];
    __shared__ float hid[64];
    const int t = threadIdx.x, w = t >> 6, c = t & 63;
    const int g = blockIdx.x;
    int lo = 0, hi = N_NODES;
    while (lo < hi) { int mid = (lo + hi) >> 1; if (batch[mid] < g) lo = mid + 1; else hi = mid; }
    int start = lo;
    hi = N_NODES;
    while (lo < hi) { int mid = (lo + hi) >> 1; if (batch[mid] < g + 1) lo = mid + 1; else hi = mid; }
    int end = lo;

    float s = 0.f, m = -3.4e38f;
    for (int i = start + w; i < end; i += 4) {
        float v = __half2float(h[(size_t)i * 64 + c]);
        s += v;
        m = fmaxf(m, v);
    }
    psum[w][c] = s;
    pmax[w][c] = m;
    __syncthreads();
    if (w == 0) {
        float ss = psum[0][c] + psum[1][c] + psum[2][c] + psum[3][c];
        float mm = fmaxf(fmaxf(pmax[0][c], pmax[1][c]), fmaxf(pmax[2][c], pmax[3][c]));
        int cnt = end - start;
        pool[c] = ss / fmaxf((float)cnt, 1.f);
        pool[64 + c] = (cnt > 0) ? mm : 0.f;
    }
    __syncthreads();
    if (t < 64) {
        float z = bc1[t];
#pragma unroll 8
        for (int k = 0; k < 128; ++k) z = fmaf(pool[k], Wc1[k * 64 + t], z);
        hid[t] = fmaxf(z, 0.f);
    }
    __syncthreads();
    if (t < N_CLS) {
        float z = bc2[t];
#pragma unroll
        for (int k = 0; k < 64; ++k) z = fmaf(hid[k], Wc2[k * N_CLS + t], z);
        out[g * N_CLS + t] = z;
    }
}

extern "C" void kernel_launch(void* const* d_in, const int* in_sizes, int n_in,
                              void* d_out, int out_size, void* d_ws, size_t ws_size,
                              hipStream_t stream) {
    const float* x     = (const float*)d_in[0];
    const int*   ei    = (const int*)d_in[1];
    const float* ea    = (const float*)d_in[2];
    const int*   batch = (const int*)d_in[3];
    const float* We1 = (const float*)d_in[4],  *be1 = (const float*)d_in[5];
    const float* We2 = (const float*)d_in[6],  *be2 = (const float*)d_in[7];
    const float* We3 = (const float*)d_in[8],  *be3 = (const float*)d_in[9];
    const float* W1 = (const float*)d_in[10], *b1 = (const float*)d_in[11];
    const float* g1 = (const float*)d_in[12], *bt1 = (const float*)d_in[13];
    const float* rm1 = (const float*)d_in[14], *rv1 = (const float*)d_in[15];
    const float* W2 = (const float*)d_in[16], *b2 = (const float*)d_in[17];
    const float* g2 = (const float*)d_in[18], *bt2 = (const float*)d_in[19];
    const float* rm2 = (const float*)d_in[20], *rv2 = (const float*)d_in[21];
    const float* W3 = (const float*)d_in[22], *b3 = (const float*)d_in[23];
    const float* g3 = (const float*)d_in[24], *bt3 = (const float*)d_in[25];
    const float* rm3 = (const float*)d_in[26], *rv3 = (const float*)d_in[27];
    const float* Wr = (const float*)d_in[28], *br = (const float*)d_in[29];
    const float* Wc1 = (const float*)d_in[30], *bc1 = (const float*)d_in[31];
    const float* Wc2 = (const float*)d_in[32], *bc2 = (const float*)d_in[33];

    int* off    = (int*)d_ws;                   // N+4
    int* gcount = off + (N_NODES + 4);          // 1024 (NB=1000, zero-padded)
    int* bbase  = gcount + 1024;                // 1024
    int2* edges = (int2*)(bbase + 1024);        // E * 8B packed records
    int2* stage = edges + E_EDGES;              // NB*BCAP * 8B fixed bucket regions
    __half* hA  = (__half*)(stage + (size_t)NB * BCAP);  // N*64 fp16
    __half* hB  = hA + (size_t)N_NODES * 64;    // N*64 fp16
    unsigned char* hA8 = (unsigned char*)(hB + (size_t)N_NODES * 64);  // (N+1)*64 fp8
    unsigned char* hB8 = hA8 + (size_t)(N_NODES + 1) * 64;             // (N+1)*64 fp8
    __half* x16 = (__half*)(hB8 + (size_t)(N_NODES + 1) * 64);         // (N+1)*16 fp16

    hipMemsetAsync(gcount, 0, 1024 * sizeof(int), stream);
    // sentinel fp8 rows: 0xFE = -448 e4m3fn -> ReLU kills tail-edge messages
    hipMemsetAsync(hA8 + (size_t)N_NODES * 64, 0xFE, 64, stream);
    hipMemsetAsync(hB8 + (size_t)N_NODES * 64, 0xFE, 64, stream);

    const int* src = ei;
    const int* dst = ei + E_EDGES;

    k_pack_x<<<((N_NODES + 1) * 16 + 255) / 256, 256, 0, stream>>>(x, x16);
    k_bin<<<E_EDGES / TILE, 512, 0, stream>>>(src, dst, (const float2*)ea, gcount, stage);
    k_bscan<<<1, 256, 0, stream>>>(gcount, bbase, off);
    k_final<<<NB, 256, 0, stream>>>(gcount, bbase, stage, off, edges);

    k_gine12<<<N_NODES / (4 * NPW12), 256, 0, stream>>>(x, x16, hA, hA8, off, edges,
                                                        We1, be1, W1, b1, g1, bt1, rm1, rv1, Wr, br);
    const int g64_blocks = N_NODES / (4 * NPW);  // 4000
    k_gine64<<<g64_blocks, 256, 0, stream>>>(hA, hA8, hB, hB8, off, edges,
                                             We2, be2, W2, b2, g2, bt2, rm2, rv2);
    k_gine64<<<g64_blocks, 256, 0, stream>>>(hB, hB8, hA, hA8, off, edges,
                                             We3, be3, W3, b3, g3, bt3, rm3, rv3);
    k_pool<<<G_GRAPHS, 256, 0, stream>>>(hA, batch, Wc1, bc1, Wc2, bc2, (float*)d_out);
}

// Round 17
// 417.703 us; speedup vs baseline: 1.1018x; 1.0116x over previous
//
#include <hip/hip_runtime.h>
#include <hip/hip_bf16.h>
#include <hip/hip_fp16.h>

#define N_NODES 128000
#define E_EDGES 2048000
#define G_GRAPHS 512
#define D_IN 12
#define D_H 64
#define N_CLS 10
#define BN_EPS 1e-5f
#define NB 1000        // buckets = dst >> 7 (128-node ranges)
#define BCAP 2560      // fixed records per bucket region
#define TILE 8192      // edges per k_bin block (250 blocks)
#define NPW 8          // nodes per wave in gine64
#define NPW12 4        // nodes per wave in gine12

typedef _Float16 h2vec __attribute__((ext_vector_type(2)));
typedef _Float16 h4vec __attribute__((ext_vector_type(4)));

__device__ __forceinline__ unsigned char f32_to_fp8(float v) {
    return (unsigned char)(__builtin_amdgcn_cvt_pk_fp8_f32(v, v, 0, false) & 0xff);
}

// ---------------- CSR build: bucket counting-sort ----------------
// Sort-then-write (r8), 512 threads (r16). r17: register-batched global loads —
// k_bin profiled at VALUBusy ~3% (97% stall/wave); issue 16-32 loads back-to-back
// per thread (r6/r10-proven static-array pattern) to raise per-wave MLP.

__global__ __launch_bounds__(512) void k_bin(const int* __restrict__ src, const int* __restrict__ dst,
                                             const float2* __restrict__ attr, int* __restrict__ gcount,
                                             int2* __restrict__ stage) {
    __shared__ int hist[NB];
    __shared__ int base_s[NB];
    __shared__ int bscan[NB];                // block-local sorted start per bucket
    __shared__ int rk[TILE];                 // packed b(10)<<20 | dstLow(7)<<13 | rank(13)
    __shared__ unsigned short sorted[TILE];  // sorted position -> edge idx
    __shared__ int psum[512];
    const int t = threadIdx.x;
    const int e0 = blockIdx.x * TILE;
    for (int i = t; i < NB; i += 512) hist[i] = 0;
    __syncthreads();
    // pass 1: batch all 16 dst loads into registers (back-to-back, 16 in flight)
    int dv[16];
#pragma unroll
    for (int j = 0; j < 16; ++j) dv[j] = dst[e0 + t + j * 512];
#pragma unroll
    for (int j = 0; j < 16; ++j) {
        int d = dv[j];
        int b = d >> 7;
        int r = atomicAdd(&hist[b], 1);
        rk[t + j * 512] = (b << 20) | ((d & 127) << 13) | r;
    }
    __syncthreads();
    // block-local exclusive scan over NB buckets (each thread owns 2)
    int h0 = (t * 2     < NB) ? hist[t * 2]     : 0;
    int h1 = (t * 2 + 1 < NB) ? hist[t * 2 + 1] : 0;
    int s = h0 + h1;
    psum[t] = s;
    __syncthreads();
    for (int off = 1; off < 512; off <<= 1) {
        int x = 0;
        if (t >= off) x = psum[t - off];
        __syncthreads();
        psum[t] += x;
        __syncthreads();
    }
    int base = psum[t] - s;  // exclusive
    if (t * 2     < NB) bscan[t * 2]     = base;
    if (t * 2 + 1 < NB) bscan[t * 2 + 1] = base + h0;
    for (int i = t; i < NB; i += 512) {
        int cb = hist[i];
        base_s[i] = i * BCAP + ((cb > 0) ? atomicAdd(&gcount[i], cb) : 0);
    }
    __syncthreads();
    // inverse permutation: sorted position -> edge index (LDS only)
    for (int i = t; i < TILE; i += 512) {
        int pr = rk[i];
        int b = pr >> 20, r = pr & 8191;
        sorted[bscan[b] + r] = (unsigned short)i;
    }
    __syncthreads();
    // pass 4: batch LDS reads, then 32 global loads back-to-back, then stores
    int idxv[16], prv[16];
#pragma unroll
    for (int j = 0; j < 16; ++j) {
        int i = sorted[t + j * 512];
        idxv[j] = i;
        prv[j] = rk[i];
    }
    unsigned long long av[16];
    int sv[16];
#pragma unroll
    for (int j = 0; j < 16; ++j) {
        av[j] = *(const unsigned long long*)&attr[e0 + idxv[j]];
        sv[j] = src[e0 + idxv[j]];
    }
#pragma unroll
    for (int j = 0; j < 16; ++j) {
        int pr = prv[j];
        int b = pr >> 20, dl = (pr >> 13) & 127, r = pr & 8191;
        float2 a = *(float2*)&av[j];
        __half2 h2 = __floats2half2_rn(a.x, a.y);
        stage[base_s[b] + r] = make_int2(sv[j] | (dl << 17), *(int*)&h2);
    }
}

__global__ __launch_bounds__(256) void k_bscan(const int* __restrict__ gcount, int* __restrict__ bbase,
                                               int* __restrict__ offsets) {
    __shared__ int sm[256];
    const int t = threadIdx.x;
    int c0 = gcount[t * 4], c1 = gcount[t * 4 + 1], c2 = gcount[t * 4 + 2], c3 = gcount[t * 4 + 3];
    int s = c0 + c1 + c2 + c3;
    sm[t] = s;
    __syncthreads();
    for (int off = 1; off < 256; off <<= 1) {
        int x = 0;
        if (t >= off) x = sm[t - off];
        __syncthreads();
        sm[t] += x;
        __syncthreads();
    }
    int base = sm[t] - s;  // exclusive
    if (t * 4 < NB)     bbase[t * 4]     = base;
    if (t * 4 + 1 < NB) bbase[t * 4 + 1] = base + c0;
    if (t * 4 + 2 < NB) bbase[t * 4 + 2] = base + c0 + c1;
    if (t * 4 + 3 < NB) bbase[t * 4 + 3] = base + c0 + c1 + c2;
    if (t == 255) offsets[N_NODES] = sm[255];
}

__global__ __launch_bounds__(256) void k_final(const int* __restrict__ gcount, const int* __restrict__ bbase,
                                               const int2* __restrict__ stage,
                                               int* __restrict__ offsets, int2* __restrict__ edges) {
    __shared__ int2 recs[BCAP];   // 20.5 KB
    __shared__ int cnt[128];
    __shared__ int incl[128];
    const int b = blockIdx.x, t = threadIdx.x;
    const int count = gcount[b];
    const int base = bbase[b];
    if (t < 128) cnt[t] = 0;
    __syncthreads();
    for (int i = t; i < count; i += 256) {
        int2 r = stage[b * BCAP + i];
        recs[i] = r;
        atomicAdd(&cnt[(r.x >> 17) & 127], 1);
    }
    __syncthreads();
    if (t < 128) incl[t] = cnt[t];
    __syncthreads();
    for (int off = 1; off < 128; off <<= 1) {   // parallel Hillis-Steele over 128
        int x = 0;
        if (t >= off && t < 128) x = incl[t - off];
        __syncthreads();
        if (t < 128) incl[t] += x;
        __syncthreads();
    }
    if (t < 128) {
        int ex = incl[t] - cnt[t];
        offsets[b * 128 + t] = base + ex;
        cnt[t] = ex;   // becomes the placement cursor
    }
    __syncthreads();
    for (int i = t; i < count; i += 256) {
        int2 r = recs[i];
        int dl = (r.x >> 17) & 127;
        int p = atomicAdd(&cnt[dl], 1);
        edges[base + p] = make_int2(r.x & 0x1FFFF, r.y);
    }
}

// pack x [N,12] fp32 -> [N+1,16] fp16 (channels 12..15 = 0); row N = sentinel -3e4
__global__ __launch_bounds__(256) void k_pack_x(const float* __restrict__ x, __half* __restrict__ x16) {
    int idx = blockIdx.x * 256 + threadIdx.x;
    if (idx >= (N_NODES + 1) * 16) return;
    int n = idx >> 4, ch = idx & 15;
    float v = (n == N_NODES) ? -30000.f : ((ch < D_IN) ? x[n * D_IN + ch] : 0.f);
    x16[idx] = __float2half(v);
}

// ---------------- Layer 1 (12-dim input, 64-dim output; fp16+fp8 out) ----------------
// 8 edges per dword load (32B row = 8 dwords); lane l = edge-slot (l>>3), channel-pair (l&7).
// r3-proven load structure (FROZEN — restructuring failed 3x: r4/r5/r11).
__global__ __launch_bounds__(256) void k_gine12(
    const float* __restrict__ x, const __half* __restrict__ x16,
    __half* __restrict__ hout, unsigned char* __restrict__ hout8,
    const int* __restrict__ off, const int2* __restrict__ edges,
    const float* __restrict__ We1, const float* __restrict__ be1,
    const float* __restrict__ W1, const float* __restrict__ b1,
    const float* __restrict__ g1, const float* __restrict__ bt1,
    const float* __restrict__ rm1, const float* __restrict__ rv1,
    const float* __restrict__ Wr, const float* __restrict__ br) {
    __shared__ float W1lds[D_IN * 64];
    __shared__ float Wrlds[D_IN * 64];
    __shared__ float uacc[4][16];
    __shared__ float u_lds[4][D_IN];
    __shared__ float x_lds[4][D_IN];
    const int t = threadIdx.x, w = t >> 6, c = t & 63;
    const int asb = (c >> 3) << 2;    // bpermute base: edge-slot
    const int dwoff = (c & 7) << 2;   // dword byte offset within 32B row
    const int ch0 = (c & 7) << 1;     // this lane's channel pair
    for (int i = t; i < D_IN * 64; i += 256) {
        W1lds[i] = W1[i];
        Wrlds[i] = Wr[i];
    }
    h2vec wp0 = {(_Float16)0.f, (_Float16)0.f}, wp1 = wp0;
    float bp0 = 0.f, bp1 = 0.f;
    if (ch0 < D_IN)     { wp0[0] = (_Float16)We1[ch0];     wp0[1] = (_Float16)We1[D_IN + ch0];     bp0 = be1[ch0]; }
    if (ch0 + 1 < D_IN) { wp1[0] = (_Float16)We1[ch0 + 1]; wp1[1] = (_Float16)We1[D_IN + ch0 + 1]; bp1 = be1[ch0 + 1]; }
    const float sj = g1[c] * rsqrtf(rv1[c] + BN_EPS);
    const float cj = (b1[c] - rm1[c]) * sj + bt1[c];
    const float brj = br[c];
    __syncthreads();

    // XCD swizzle: 8000 blocks = 8 XCDs x 1000; same-XCD blocks -> contiguous nodes
    const int swz = (blockIdx.x & 7) * 1000 + (blockIdx.x >> 3);
    const int wbase = (swz * 4 + w) * NPW12;
    for (int nn = 0; nn < NPW12; ++nn) {
        const int n = wbase + nn;
        const int rs = off[n], re = off[n + 1];
        float a0 = 0.f, a1 = 0.f;
        for (int base = rs; base < re; base += 64) {
            const int cnt = min(64, re - base);
            int2 rec = make_int2(N_NODES, 0);
            if (c < cnt) rec = edges[base + c];
            for (int j0 = 0; j0 < cnt; j0 += 16) {
                const int ab = (j0 << 2) + asb;
                int s0 = __builtin_amdgcn_ds_bpermute(ab,      rec.x);
                int s1 = __builtin_amdgcn_ds_bpermute(ab + 32, rec.x);
                int e0 = __builtin_amdgcn_ds_bpermute(ab,      rec.y);
                int e1 = __builtin_amdgcn_ds_bpermute(ab + 32, rec.y);
                int ld0 = *(const int*)((const char*)x16 + ((s0 << 5) + dwoff));
                int ld1 = *(const int*)((const char*)x16 + ((s1 << 5) + dwoff));
                {
                    h2vec hv = __builtin_bit_cast(h2vec, ld0);
                    h2vec av = __builtin_bit_cast(h2vec, e0);
                    float q0 = __builtin_amdgcn_fdot2(av, wp0, bp0, false);
                    float q1 = __builtin_amdgcn_fdot2(av, wp1, bp1, false);
                    a0 += fmaxf((float)hv[0] + q0, 0.f);
                    a1 += fmaxf((float)hv[1] + q1, 0.f);
                }
                {
                    h2vec hv = __builtin_bit_cast(h2vec, ld1);
                    h2vec av = __builtin_bit_cast(h2vec, e1);
                    float q0 = __builtin_amdgcn_fdot2(av, wp0, bp0, false);
                    float q1 = __builtin_amdgcn_fdot2(av, wp1, bp1, false);
                    a0 += fmaxf((float)hv[0] + q0, 0.f);
                    a1 += fmaxf((float)hv[1] + q1, 0.f);
                }
            }
        }
        // fold 8 edge-slot groups (lane bits 3,4,5)
        a0 += __shfl_xor(a0, 8);  a1 += __shfl_xor(a1, 8);
        a0 += __shfl_xor(a0, 16); a1 += __shfl_xor(a1, 16);
        a0 += __shfl_xor(a0, 32); a1 += __shfl_xor(a1, 32);
        uacc[w][ch0] = a0;        // duplicate writers, same value
        uacc[w][ch0 + 1] = a1;
        if (c < D_IN) {
            float xc = x[(size_t)n * D_IN + c];
            x_lds[w][c] = xc;
            u_lds[w][c] = xc + uacc[w][c];
        }
        float z = 0.f, r = 0.f;
#pragma unroll
        for (int k = 0; k < D_IN; ++k) {
            z = fmaf(u_lds[w][k], W1lds[k * 64 + c], z);
            r = fmaf(x_lds[w][k], Wrlds[k * 64 + c], r);
        }
        float v = fmaxf(fmaf(z, sj, cj), 0.f) + r + brj;
        hout[(size_t)n * 64 + c] = __float2half(v);
        hout8[(size_t)n * 64 + c] = f32_to_fp8(v);
    }
}

// ---------------- Layers 2/3: fp8 gather, depth-1 pipeline + conditional early chunk-1 ----------------
// Lane l = edge-slot (l>>4), channel-quad (l&15). Loaded dword IS the accumulation layout.
// Chunk-0 (slots 0-15) prefetched one node ahead (r10 ping-pong). Chunk-1 (slots 16-31)
// issued EARLY only when deg>16 (wave-uniform branch) so its gather latency hides under
// chunk-0's consume; zero added work for deg<=16 nodes. Sentinel-killed tails (r7-verified).
__global__ __launch_bounds__(256) void k_gine64(
    const __half* __restrict__ hin, const unsigned char* __restrict__ hin8,
    __half* __restrict__ hout, unsigned char* __restrict__ hout8,
    const int* __restrict__ off, const int2* __restrict__ edges,
    const float* __restrict__ We, const float* __restrict__ be,
    const float* __restrict__ W, const float* __restrict__ b,
    const float* __restrict__ g, const float* __restrict__ bt,
    const float* __restrict__ rm, const float* __restrict__ rv) {
    __shared__ _Float16 WtL[64][68];   // transposed W, fp16
    __shared__ _Float16 uL[4][64];
    const int t = threadIdx.x, w = t >> 6, c = t & 63;
    for (int i = t; i < 4096; i += 256) {
        int k = i >> 6, cc = i & 63;
        WtL[cc][k] = (_Float16)W[i];   // W[k*64+cc]
    }
    const int asb   = (c >> 4) << 2;   // bpermute base: edge-slot
    const int dwoff = (c & 15) << 2;   // dword byte offset within 64B row
    const int q4    = (c & 15) << 2;   // base channel of this lane's quad
    h2vec weq[4];
    float beq[4];
#pragma unroll
    for (int j = 0; j < 4; ++j) {
        weq[j][0] = (_Float16)We[q4 + j];
        weq[j][1] = (_Float16)We[64 + q4 + j];
        beq[j] = be[q4 + j];
    }
    const float sj = g[c] * rsqrtf(rv[c] + BN_EPS);
    const float cj = (b[c] - rm[c]) * sj + bt[c];
    __syncthreads();

    // XCD swizzle: 4000 blocks = 8 XCDs x 500; same-XCD blocks -> contiguous nodes
    const int swz = (blockIdx.x & 7) * 500 + (blockIdx.x >> 3);
    const int wbase = (swz * 4 + w) * NPW;

    int offv[NPW + 1];
#pragma unroll
    for (int i = 0; i <= NPW; ++i) offv[i] = off[wbase + i];

    int2 rec0[NPW];                    // first-block records, all nodes
#pragma unroll
    for (int i = 0; i < NPW; ++i) {
        int2 r = make_int2(N_NODES, 0);
        if (c < offv[i + 1] - offv[i]) r = edges[offv[i] + c];
        rec0[i] = r;
    }

    int ldP[2][4], eyP[2][4];          // ping-pong chunk-0 gather sets
#define ISSUE(P, I)                                                              \
    {                                                                            \
        _Pragma("unroll")                                                        \
        for (int j = 0; j < 4; ++j) {                                            \
            int sx = __builtin_amdgcn_ds_bpermute(asb + (j << 4), rec0[I].x);    \
            eyP[P][j] = __builtin_amdgcn_ds_bpermute(asb + (j << 4), rec0[I].y); \
            ldP[P][j] = *(const int*)(hin8 + ((sx << 6) + dwoff));               \
        }                                                                        \
    }
#define CONSUME(LD, EA)                                                          \
    {                                                                            \
        h2vec av = __builtin_bit_cast(h2vec, EA);                                \
        float q0 = __builtin_amdgcn_fdot2(av, weq[0], beq[0], false);            \
        float q1 = __builtin_amdgcn_fdot2(av, weq[1], beq[1], false);            \
        float q2 = __builtin_amdgcn_fdot2(av, weq[2], beq[2], false);            \
        float q3 = __builtin_amdgcn_fdot2(av, weq[3], beq[3], false);            \
        acc0 += fmaxf(__builtin_amdgcn_cvt_f32_fp8(LD, 0) + q0, 0.f);            \
        acc1 += fmaxf(__builtin_amdgcn_cvt_f32_fp8(LD, 1) + q1, 0.f);            \
        acc2 += fmaxf(__builtin_amdgcn_cvt_f32_fp8(LD, 2) + q2, 0.f);            \
        acc3 += fmaxf(__builtin_amdgcn_cvt_f32_fp8(LD, 3) + q3, 0.f);            \
    }

    ISSUE(0, 0)
#pragma unroll
    for (int nn = 0; nn < NPW; ++nn) {
        const int p = nn & 1;
        if (nn + 1 < NPW) ISSUE(p ^ 1, nn + 1)   // overlap next node's chunk-0 gathers
        const int n = wbase + nn;
        const int rs = offv[nn], re = offv[nn + 1];
        const int cnt0 = min(64, re - rs);
        // conditional early chunk-1 (slots 16-31): wave-uniform branch, ~47% of nodes.
        int ldQ[4], eyQ[4];
        const bool hasQ = cnt0 > 16;
        if (hasQ) {
#pragma unroll
            for (int j = 0; j < 4; ++j) {
                const int ab = 64 + asb + (j << 4);
                int sx = __builtin_amdgcn_ds_bpermute(ab, rec0[nn].x);
                eyQ[j] = __builtin_amdgcn_ds_bpermute(ab, rec0[nn].y);
                ldQ[j] = *(const int*)(hin8 + ((sx << 6) + dwoff));
            }
        }
        const float hc = __half2float(hin[(size_t)n * 64 + c]);
        float acc0 = 0.f, acc1 = 0.f, acc2 = 0.f, acc3 = 0.f;
        CONSUME(ldP[p][0], eyP[p][0])
        CONSUME(ldP[p][1], eyP[p][1])
        CONSUME(ldP[p][2], eyP[p][2])
        CONSUME(ldP[p][3], eyP[p][3])
        if (hasQ) {
            CONSUME(ldQ[0], eyQ[0])
            CONSUME(ldQ[1], eyQ[1])
            CONSUME(ldQ[2], eyQ[2])
            CONSUME(ldQ[3], eyQ[3])
        }
        // remainder chunks of first block (deg > 32, ~0.01% of nodes)
        for (int j0 = 32; j0 < cnt0; j0 += 16) {
            const int ab = (j0 << 2) + asb;
            int s0 = __builtin_amdgcn_ds_bpermute(ab,      rec0[nn].x);
            int s1 = __builtin_amdgcn_ds_bpermute(ab + 16, rec0[nn].x);
            int s2 = __builtin_amdgcn_ds_bpermute(ab + 32, rec0[nn].x);
            int s3 = __builtin_amdgcn_ds_bpermute(ab + 48, rec0[nn].x);
            int e0 = __builtin_amdgcn_ds_bpermute(ab,      rec0[nn].y);
            int e1 = __builtin_amdgcn_ds_bpermute(ab + 16, rec0[nn].y);
            int e2 = __builtin_amdgcn_ds_bpermute(ab + 32, rec0[nn].y);
            int e3 = __builtin_amdgcn_ds_bpermute(ab + 48, rec0[nn].y);
            int ld0 = *(const int*)(hin8 + ((s0 << 6) + dwoff));
            int ld1 = *(const int*)(hin8 + ((s1 << 6) + dwoff));
            int ld2 = *(const int*)(hin8 + ((s2 << 6) + dwoff));
            int ld3 = *(const int*)(hin8 + ((s3 << 6) + dwoff));
            CONSUME(ld0, e0)
            CONSUME(ld1, e1)
            CONSUME(ld2, e2)
            CONSUME(ld3, e3)
        }
        // deg > 64 tail blocks (rare) — verbatim r3
        for (int base = rs + 64; base < re; base += 64) {
            const int cnt = min(64, re - base);
            int2 rec = make_int2(N_NODES, 0);
            if (c < cnt) rec = edges[base + c];
            for (int j0 = 0; j0 < cnt; j0 += 16) {
                const int ab = (j0 << 2) + asb;
                int s0 = __builtin_amdgcn_ds_bpermute(ab,      rec.x);
                int s1 = __builtin_amdgcn_ds_bpermute(ab + 16, rec.x);
                int s2 = __builtin_amdgcn_ds_bpermute(ab + 32, rec.x);
                int s3 = __builtin_amdgcn_ds_bpermute(ab + 48, rec.x);
                int e0 = __builtin_amdgcn_ds_bpermute(ab,      rec.y);
                int e1 = __builtin_amdgcn_ds_bpermute(ab + 16, rec.y);
                int e2 = __builtin_amdgcn_ds_bpermute(ab + 32, rec.y);
                int e3 = __builtin_amdgcn_ds_bpermute(ab + 48, rec.y);
                int ld0 = *(const int*)(hin8 + ((s0 << 6) + dwoff));
                int ld1 = *(const int*)(hin8 + ((s1 << 6) + dwoff));
                int ld2 = *(const int*)(hin8 + ((s2 << 6) + dwoff));
                int ld3 = *(const int*)(hin8 + ((s3 << 6) + dwoff));
                CONSUME(ld0, e0)
                CONSUME(ld1, e1)
                CONSUME(ld2, e2)
                CONSUME(ld3, e3)
            }
        }
        // fold 4 edge-slot groups (lane bits 4,5)
        acc0 += __shfl_xor(acc0, 16); acc1 += __shfl_xor(acc1, 16);
        acc2 += __shfl_xor(acc2, 16); acc3 += __shfl_xor(acc3, 16);
        acc0 += __shfl_xor(acc0, 32); acc1 += __shfl_xor(acc1, 32);
        acc2 += __shfl_xor(acc2, 32); acc3 += __shfl_xor(acc3, 32);
        h4vec aq = {(_Float16)acc0, (_Float16)acc1, (_Float16)acc2, (_Float16)acc3};
        *(h4vec*)&uL[w][q4] = aq;            // duplicate writers, same value
        float u = hc + (float)uL[w][c];      // per-channel center add
        uL[w][c] = (_Float16)u;
        float z = 0.f;
        const h4vec* u4p = (const h4vec*)uL[w];
        const h4vec* wt4p = (const h4vec*)&WtL[c][0];
#pragma unroll
        for (int k4 = 0; k4 < 16; ++k4) {
            h4vec uu = u4p[k4];
            h4vec ww = wt4p[k4];
            h2vec ul = __builtin_shufflevector(uu, uu, 0, 1);
            h2vec uh = __builtin_shufflevector(uu, uu, 2, 3);
            h2vec wl = __builtin_shufflevector(ww, ww, 0, 1);
            h2vec wh = __builtin_shufflevector(ww, ww, 2, 3);
            z = __builtin_amdgcn_fdot2(ul, wl, z, false);
            z = __builtin_amdgcn_fdot2(uh, wh, z, false);
        }
        float v = fmaxf(fmaf(z, sj, cj), 0.f) + hc;
        hout[(size_t)n * 64 + c] = __float2half(v);
        hout8[(size_t)n * 64 + c] = f32_to_fp8(v);
    }
#undef CONSUME
#undef ISSUE
}

// ---------------- Pool (mean+max per graph) + classifier ----------------
__global__ __launch_bounds__(256) void k_pool(
    const __half* __restrict__ h, const int* __restrict__ batch,
    const float* __restrict__ Wc1, const float* __restrict__ bc1,
    const float* __restrict__ Wc2, const float* __restrict__ bc2,
    float* __restrict__ out) {
    __shared__ float psum[4][64];
    __shared__ float pmax[4][64];
    __shared__ float pool[128];
    __shared__ float hid[64];
    const int t = threadIdx.x, w = t >> 6, c = t & 63;
    const int g = blockIdx.x;
    int lo = 0, hi = N_NODES;
    while (lo < hi) { int mid = (lo + hi) >> 1; if (batch[mid] < g) lo = mid + 1; else hi = mid; }
    int start = lo;
    hi = N_NODES;
    while (lo < hi) { int mid = (lo + hi) >> 1; if (batch[mid] < g + 1) lo = mid + 1; else hi = mid; }
    int end = lo;

    float s = 0.f, m = -3.4e38f;
    for (int i = start + w; i < end; i += 4) {
        float v = __half2float(h[(size_t)i * 64 + c]);
        s += v;
        m = fmaxf(m, v);
    }
    psum[w][c] = s;
    pmax[w][c] = m;
    __syncthreads();
    if (w == 0) {
        float ss = psum[0][c] + psum[1][c] + psum[2][c] + psum[3][c];
        float mm = fmaxf(fmaxf(pmax[0][c], pmax[1][c]), fmaxf(pmax[2][c], pmax[3][c]));
        int cnt = end - start;
        pool[c] = ss / fmaxf((float)cnt, 1.f);
        pool[64 + c] = (cnt > 0) ? mm : 0.f;
    }
    __syncthreads();
    if (t < 64) {
        float z = bc1[t];
#pragma unroll 8
        for (int k = 0; k < 128; ++k) z = fmaf(pool[k], Wc1[k * 64 + t], z);
        hid[t] = fmaxf(z, 0.f);
    }
    __syncthreads();
    if (t < N_CLS) {
        float z = bc2[t];
#pragma unroll
        for (int k = 0; k < 64; ++k) z = fmaf(hid[k], Wc2[k * N_CLS + t], z);
        out[g * N_CLS + t] = z;
    }
}

extern "C" void kernel_launch(void* const* d_in, const int* in_sizes, int n_in,
                              void* d_out, int out_size, void* d_ws, size_t ws_size,
                              hipStream_t stream) {
    const float* x     = (const float*)d_in[0];
    const int*   ei    = (const int*)d_in[1];
    const float* ea    = (const float*)d_in[2];
    const int*   batch = (const int*)d_in[3];
    const float* We1 = (const float*)d_in[4],  *be1 = (const float*)d_in[5];
    const float* We2 = (const float*)d_in[6],  *be2 = (const float*)d_in[7];
    const float* We3 = (const float*)d_in[8],  *be3 = (const float*)d_in[9];
    const float* W1 = (const float*)d_in[10], *b1 = (const float*)d_in[11];
    const float* g1 = (const float*)d_in[12], *bt1 = (const float*)d_in[13];
    const float* rm1 = (const float*)d_in[14], *rv1 = (const float*)d_in[15];
    const float* W2 = (const float*)d_in[16], *b2 = (const float*)d_in[17];
    const float* g2 = (const float*)d_in[18], *bt2 = (const float*)d_in[19];
    const float* rm2 = (const float*)d_in[20], *rv2 = (const float*)d_in[21];
    const float* W3 = (const float*)d_in[22], *b3 = (const float*)d_in[23];
    const float* g3 = (const float*)d_in[24], *bt3 = (const float*)d_in[25];
    const float* rm3 = (const float*)d_in[26], *rv3 = (const float*)d_in[27];
    const float* Wr = (const float*)d_in[28], *br = (const float*)d_in[29];
    const float* Wc1 = (const float*)d_in[30], *bc1 = (const float*)d_in[31];
    const float* Wc2 = (const float*)d_in[32], *bc2 = (const float*)d_in[33];

    int* off    = (int*)d_ws;                   // N+4
    int* gcount = off + (N_NODES + 4);          // 1024 (NB=1000, zero-padded)
    int* bbase  = gcount + 1024;                // 1024
    int2* edges = (int2*)(bbase + 1024);        // E * 8B packed records
    int2* stage = edges + E_EDGES;              // NB*BCAP * 8B fixed bucket regions
    __half* hA  = (__half*)(stage + (size_t)NB * BCAP);  // N*64 fp16
    __half* hB  = hA + (size_t)N_NODES * 64;    // N*64 fp16
    unsigned char* hA8 = (unsigned char*)(hB + (size_t)N_NODES * 64);  // (N+1)*64 fp8
    unsigned char* hB8 = hA8 + (size_t)(N_NODES + 1) * 64;             // (N+1)*64 fp8
    __half* x16 = (__half*)(hB8 + (size_t)(N_NODES + 1) * 64);         // (N+1)*16 fp16

    hipMemsetAsync(gcount, 0, 1024 * sizeof(int), stream);
    // sentinel fp8 rows: 0xFE = -448 e4m3fn -> ReLU kills tail-edge messages
    hipMemsetAsync(hA8 + (size_t)N_NODES * 64, 0xFE, 64, stream);
    hipMemsetAsync(hB8 + (size_t)N_NODES * 64, 0xFE, 64, stream);

    const int* src = ei;
    const int* dst = ei + E_EDGES;

    k_pack_x<<<((N_NODES + 1) * 16 + 255) / 256, 256, 0, stream>>>(x, x16);
    k_bin<<<E_EDGES / TILE, 512, 0, stream>>>(src, dst, (const float2*)ea, gcount, stage);
    k_bscan<<<1, 256, 0, stream>>>(gcount, bbase, off);
    k_final<<<NB, 256, 0, stream>>>(gcount, bbase, stage, off, edges);

    k_gine12<<<N_NODES / (4 * NPW12), 256, 0, stream>>>(x, x16, hA, hA8, off, edges,
                                                        We1, be1, W1, b1, g1, bt1, rm1, rv1, Wr, br);
    const int g64_blocks = N_NODES / (4 * NPW);  // 4000
    k_gine64<<<g64_blocks, 256, 0, stream>>>(hA, hA8, hB, hB8, off, edges,
                                             We2, be2, W2, b2, g2, bt2, rm2, rv2);
    k_gine64<<<g64_blocks, 256, 0, stream>>>(hB, hB8, hA, hA8, off, edges,
                                             We3, be3, W3, b3, g3, bt3, rm3, rv3);
    k_pool<<<G_GRAPHS, 256, 0, stream>>>(hA, batch, Wc1, bc1, Wc2, bc2, (float*)d_out);
}

// Round 18
// 413.616 us; speedup vs baseline: 1.1126x; 1.0099x over previous
//
#include <hip/hip_runtime.h>
#include <hip/hip_bf16.h>
#include <hip/hip_fp16.h>

#define N_NODES 128000
#define E_EDGES 2048000
#define G_GRAPHS 512
#define D_IN 12
#define D_H 64
#define N_CLS 10
#define BN_EPS 1e-5f
#define NB 1000        // buckets = dst >> 7 (128-node ranges)
#define BCAP 2560      // fixed records per bucket region
#define TILE 8192      // edges per k_bin block (250 blocks)
#define NPW 8          // nodes per wave in gine64
#define NPW12 4        // nodes per wave in gine12

typedef _Float16 h2vec __attribute__((ext_vector_type(2)));
typedef _Float16 h4vec __attribute__((ext_vector_type(4)));

__device__ __forceinline__ unsigned char f32_to_fp8(float v) {
    return (unsigned char)(__builtin_amdgcn_cvt_pk_fp8_f32(v, v, 0, false) & 0xff);
}

// ---------------- CSR build: bucket counting-sort ----------------
// Sort-then-write (r8), 512 threads (r16), register-batched loads (r17).

__global__ __launch_bounds__(512) void k_bin(const int* __restrict__ src, const int* __restrict__ dst,
                                             const float2* __restrict__ attr, int* __restrict__ gcount,
                                             int2* __restrict__ stage) {
    __shared__ int hist[NB];
    __shared__ int base_s[NB];
    __shared__ int bscan[NB];                // block-local sorted start per bucket
    __shared__ int rk[TILE];                 // packed b(10)<<20 | dstLow(7)<<13 | rank(13)
    __shared__ unsigned short sorted[TILE];  // sorted position -> edge idx
    __shared__ int psum[512];
    const int t = threadIdx.x;
    const int e0 = blockIdx.x * TILE;
    for (int i = t; i < NB; i += 512) hist[i] = 0;
    __syncthreads();
    // pass 1: batch all 16 dst loads into registers (back-to-back, 16 in flight)
    int dv[16];
#pragma unroll
    for (int j = 0; j < 16; ++j) dv[j] = dst[e0 + t + j * 512];
#pragma unroll
    for (int j = 0; j < 16; ++j) {
        int d = dv[j];
        int b = d >> 7;
        int r = atomicAdd(&hist[b], 1);
        rk[t + j * 512] = (b << 20) | ((d & 127) << 13) | r;
    }
    __syncthreads();
    // block-local exclusive scan over NB buckets (each thread owns 2)
    int h0 = (t * 2     < NB) ? hist[t * 2]     : 0;
    int h1 = (t * 2 + 1 < NB) ? hist[t * 2 + 1] : 0;
    int s = h0 + h1;
    psum[t] = s;
    __syncthreads();
    for (int off = 1; off < 512; off <<= 1) {
        int x = 0;
        if (t >= off) x = psum[t - off];
        __syncthreads();
        psum[t] += x;
        __syncthreads();
    }
    int base = psum[t] - s;  // exclusive
    if (t * 2     < NB) bscan[t * 2]     = base;
    if (t * 2 + 1 < NB) bscan[t * 2 + 1] = base + h0;
    for (int i = t; i < NB; i += 512) {
        int cb = hist[i];
        base_s[i] = i * BCAP + ((cb > 0) ? atomicAdd(&gcount[i], cb) : 0);
    }
    __syncthreads();
    // inverse permutation: sorted position -> edge index (LDS only)
    for (int i = t; i < TILE; i += 512) {
        int pr = rk[i];
        int b = pr >> 20, r = pr & 8191;
        sorted[bscan[b] + r] = (unsigned short)i;
    }
    __syncthreads();
    // pass 4: batch LDS reads, then 32 global loads back-to-back, then stores
    int idxv[16], prv[16];
#pragma unroll
    for (int j = 0; j < 16; ++j) {
        int i = sorted[t + j * 512];
        idxv[j] = i;
        prv[j] = rk[i];
    }
    unsigned long long av[16];
    int sv[16];
#pragma unroll
    for (int j = 0; j < 16; ++j) {
        av[j] = *(const unsigned long long*)&attr[e0 + idxv[j]];
        sv[j] = src[e0 + idxv[j]];
    }
#pragma unroll
    for (int j = 0; j < 16; ++j) {
        int pr = prv[j];
        int b = pr >> 20, dl = (pr >> 13) & 127, r = pr & 8191;
        float2 a = *(float2*)&av[j];
        __half2 h2 = __floats2half2_rn(a.x, a.y);
        stage[base_s[b] + r] = make_int2(sv[j] | (dl << 17), *(int*)&h2);
    }
}

__global__ __launch_bounds__(256) void k_bscan(const int* __restrict__ gcount, int* __restrict__ bbase,
                                               int* __restrict__ offsets) {
    __shared__ int sm[256];
    const int t = threadIdx.x;
    int c0 = gcount[t * 4], c1 = gcount[t * 4 + 1], c2 = gcount[t * 4 + 2], c3 = gcount[t * 4 + 3];
    int s = c0 + c1 + c2 + c3;
    sm[t] = s;
    __syncthreads();
    for (int off = 1; off < 256; off <<= 1) {
        int x = 0;
        if (t >= off) x = sm[t - off];
        __syncthreads();
        sm[t] += x;
        __syncthreads();
    }
    int base = sm[t] - s;  // exclusive
    if (t * 4 < NB)     bbase[t * 4]     = base;
    if (t * 4 + 1 < NB) bbase[t * 4 + 1] = base + c0;
    if (t * 4 + 2 < NB) bbase[t * 4 + 2] = base + c0 + c1;
    if (t * 4 + 3 < NB) bbase[t * 4 + 3] = base + c0 + c1 + c2;
    if (t == 255) offsets[N_NODES] = sm[255];
}

// r18: register-batched load + placement phases (k_bin's r17 recipe).
// Batched loads are UNCONDITIONAL (full BCAP region is allocated -> safe);
// consumption stays guarded by count. Remainder loops cover count > 2048.
__global__ __launch_bounds__(256) void k_final(const int* __restrict__ gcount, const int* __restrict__ bbase,
                                               const int2* __restrict__ stage,
                                               int* __restrict__ offsets, int2* __restrict__ edges) {
    __shared__ int2 recs[BCAP];   // 20.5 KB
    __shared__ int cnt[128];
    __shared__ int incl[128];
    const int b = blockIdx.x, t = threadIdx.x;
    const int count = gcount[b];
    const int base = bbase[b];
    if (t < 128) cnt[t] = 0;
    __syncthreads();
    // batched stage loads: 8 per thread covers 2048 (back-to-back, 8 in flight)
    {
        int2 rv[8];
#pragma unroll
        for (int j = 0; j < 8; ++j) rv[j] = stage[b * BCAP + t + j * 256];
#pragma unroll
        for (int j = 0; j < 8; ++j) {
            const int i = t + j * 256;
            if (i < count) {
                recs[i] = rv[j];
                atomicAdd(&cnt[(rv[j].x >> 17) & 127], 1);
            }
        }
        for (int i = 2048 + t; i < count; i += 256) {   // remainder (count > 2048)
            int2 r = stage[b * BCAP + i];
            recs[i] = r;
            atomicAdd(&cnt[(r.x >> 17) & 127], 1);
        }
    }
    __syncthreads();
    if (t < 128) incl[t] = cnt[t];
    __syncthreads();
    for (int off = 1; off < 128; off <<= 1) {   // parallel Hillis-Steele over 128
        int x = 0;
        if (t >= off && t < 128) x = incl[t - off];
        __syncthreads();
        if (t < 128) incl[t] += x;
        __syncthreads();
    }
    if (t < 128) {
        int ex = incl[t] - cnt[t];
        offsets[b * 128 + t] = base + ex;
        cnt[t] = ex;   // becomes the placement cursor
    }
    __syncthreads();
    // batched placement: LDS reads first, then atomic+store sweep
    {
        int2 rv[8];
#pragma unroll
        for (int j = 0; j < 8; ++j) rv[j] = recs[min(t + j * 256, BCAP - 1)];
#pragma unroll
        for (int j = 0; j < 8; ++j) {
            const int i = t + j * 256;
            if (i < count) {
                int dl = (rv[j].x >> 17) & 127;
                int p = atomicAdd(&cnt[dl], 1);
                edges[base + p] = make_int2(rv[j].x & 0x1FFFF, rv[j].y);
            }
        }
        for (int i = 2048 + t; i < count; i += 256) {   // remainder
            int2 r = recs[i];
            int dl = (r.x >> 17) & 127;
            int p = atomicAdd(&cnt[dl], 1);
            edges[base + p] = make_int2(r.x & 0x1FFFF, r.y);
        }
    }
}

// pack x [N,12] fp32 -> [N+1,16] fp16 (channels 12..15 = 0); row N = sentinel -3e4
__global__ __launch_bounds__(256) void k_pack_x(const float* __restrict__ x, __half* __restrict__ x16) {
    int idx = blockIdx.x * 256 + threadIdx.x;
    if (idx >= (N_NODES + 1) * 16) return;
    int n = idx >> 4, ch = idx & 15;
    float v = (n == N_NODES) ? -30000.f : ((ch < D_IN) ? x[n * D_IN + ch] : 0.f);
    x16[idx] = __float2half(v);
}

// ---------------- Layer 1 (12-dim input, 64-dim output; fp16+fp8 out) ----------------
// 8 edges per dword load (32B row = 8 dwords); lane l = edge-slot (l>>3), channel-pair (l&7).
// r3-proven load structure (FROZEN — restructuring failed 3x: r4/r5/r11).
__global__ __launch_bounds__(256) void k_gine12(
    const float* __restrict__ x, const __half* __restrict__ x16,
    __half* __restrict__ hout, unsigned char* __restrict__ hout8,
    const int* __restrict__ off, const int2* __restrict__ edges,
    const float* __restrict__ We1, const float* __restrict__ be1,
    const float* __restrict__ W1, const float* __restrict__ b1,
    const float* __restrict__ g1, const float* __restrict__ bt1,
    const float* __restrict__ rm1, const float* __restrict__ rv1,
    const float* __restrict__ Wr, const float* __restrict__ br) {
    __shared__ float W1lds[D_IN * 64];
    __shared__ float Wrlds[D_IN * 64];
    __shared__ float uacc[4][16];
    __shared__ float u_lds[4][D_IN];
    __shared__ float x_lds[4][D_IN];
    const int t = threadIdx.x, w = t >> 6, c = t & 63;
    const int asb = (c >> 3) << 2;    // bpermute base: edge-slot
    const int dwoff = (c & 7) << 2;   // dword byte offset within 32B row
    const int ch0 = (c & 7) << 1;     // this lane's channel pair
    for (int i = t; i < D_IN * 64; i += 256) {
        W1lds[i] = W1[i];
        Wrlds[i] = Wr[i];
    }
    h2vec wp0 = {(_Float16)0.f, (_Float16)0.f}, wp1 = wp0;
    float bp0 = 0.f, bp1 = 0.f;
    if (ch0 < D_IN)     { wp0[0] = (_Float16)We1[ch0];     wp0[1] = (_Float16)We1[D_IN + ch0];     bp0 = be1[ch0]; }
    if (ch0 + 1 < D_IN) { wp1[0] = (_Float16)We1[ch0 + 1]; wp1[1] = (_Float16)We1[D_IN + ch0 + 1]; bp1 = be1[ch0 + 1]; }
    const float sj = g1[c] * rsqrtf(rv1[c] + BN_EPS);
    const float cj = (b1[c] - rm1[c]) * sj + bt1[c];
    const float brj = br[c];
    __syncthreads();

    // XCD swizzle: 8000 blocks = 8 XCDs x 1000; same-XCD blocks -> contiguous nodes
    const int swz = (blockIdx.x & 7) * 1000 + (blockIdx.x >> 3);
    const int wbase = (swz * 4 + w) * NPW12;
    for (int nn = 0; nn < NPW12; ++nn) {
        const int n = wbase + nn;
        const int rs = off[n], re = off[n + 1];
        float a0 = 0.f, a1 = 0.f;
        for (int base = rs; base < re; base += 64) {
            const int cnt = min(64, re - base);
            int2 rec = make_int2(N_NODES, 0);
            if (c < cnt) rec = edges[base + c];
            for (int j0 = 0; j0 < cnt; j0 += 16) {
                const int ab = (j0 << 2) + asb;
                int s0 = __builtin_amdgcn_ds_bpermute(ab,      rec.x);
                int s1 = __builtin_amdgcn_ds_bpermute(ab + 32, rec.x);
                int e0 = __builtin_amdgcn_ds_bpermute(ab,      rec.y);
                int e1 = __builtin_amdgcn_ds_bpermute(ab + 32, rec.y);
                int ld0 = *(const int*)((const char*)x16 + ((s0 << 5) + dwoff));
                int ld1 = *(const int*)((const char*)x16 + ((s1 << 5) + dwoff));
                {
                    h2vec hv = __builtin_bit_cast(h2vec, ld0);
                    h2vec av = __builtin_bit_cast(h2vec, e0);
                    float q0 = __builtin_amdgcn_fdot2(av, wp0, bp0, false);
                    float q1 = __builtin_amdgcn_fdot2(av, wp1, bp1, false);
                    a0 += fmaxf((float)hv[0] + q0, 0.f);
                    a1 += fmaxf((float)hv[1] + q1, 0.f);
                }
                {
                    h2vec hv = __builtin_bit_cast(h2vec, ld1);
                    h2vec av = __builtin_bit_cast(h2vec, e1);
                    float q0 = __builtin_amdgcn_fdot2(av, wp0, bp0, false);
                    float q1 = __builtin_amdgcn_fdot2(av, wp1, bp1, false);
                    a0 += fmaxf((float)hv[0] + q0, 0.f);
                    a1 += fmaxf((float)hv[1] + q1, 0.f);
                }
            }
        }
        // fold 8 edge-slot groups (lane bits 3,4,5)
        a0 += __shfl_xor(a0, 8);  a1 += __shfl_xor(a1, 8);
        a0 += __shfl_xor(a0, 16); a1 += __shfl_xor(a1, 16);
        a0 += __shfl_xor(a0, 32); a1 += __shfl_xor(a1, 32);
        uacc[w][ch0] = a0;        // duplicate writers, same value
        uacc[w][ch0 + 1] = a1;
        if (c < D_IN) {
            float xc = x[(size_t)n * D_IN + c];
            x_lds[w][c] = xc;
            u_lds[w][c] = xc + uacc[w][c];
        }
        float z = 0.f, r = 0.f;
#pragma unroll
        for (int k = 0; k < D_IN; ++k) {
            z = fmaf(u_lds[w][k], W1lds[k * 64 + c], z);
            r = fmaf(x_lds[w][k], Wrlds[k * 64 + c], r);
        }
        float v = fmaxf(fmaf(z, sj, cj), 0.f) + r + brj;
        hout[(size_t)n * 64 + c] = __float2half(v);
        hout8[(size_t)n * 64 + c] = f32_to_fp8(v);
    }
}

// ---------------- Layers 2/3: fp8 gather, depth-1 pipeline + conditional early chunk-1 ----------------
// Lane l = edge-slot (l>>4), channel-quad (l&15). Loaded dword IS the accumulation layout.
// Chunk-0 (slots 0-15) prefetched one node ahead (r10 ping-pong). Chunk-1 (slots 16-31)
// issued EARLY only when deg>16 (wave-uniform branch) so its gather latency hides under
// chunk-0's consume; zero added work for deg<=16 nodes. Sentinel-killed tails (r7-verified).
__global__ __launch_bounds__(256) void k_gine64(
    const __half* __restrict__ hin, const unsigned char* __restrict__ hin8,
    __half* __restrict__ hout, unsigned char* __restrict__ hout8,
    const int* __restrict__ off, const int2* __restrict__ edges,
    const float* __restrict__ We, const float* __restrict__ be,
    const float* __restrict__ W, const float* __restrict__ b,
    const float* __restrict__ g, const float* __restrict__ bt,
    const float* __restrict__ rm, const float* __restrict__ rv) {
    __shared__ _Float16 WtL[64][68];   // transposed W, fp16
    __shared__ _Float16 uL[4][64];
    const int t = threadIdx.x, w = t >> 6, c = t & 63;
    for (int i = t; i < 4096; i += 256) {
        int k = i >> 6, cc = i & 63;
        WtL[cc][k] = (_Float16)W[i];   // W[k*64+cc]
    }
    const int asb   = (c >> 4) << 2;   // bpermute base: edge-slot
    const int dwoff = (c & 15) << 2;   // dword byte offset within 64B row
    const int q4    = (c & 15) << 2;   // base channel of this lane's quad
    h2vec weq[4];
    float beq[4];
#pragma unroll
    for (int j = 0; j < 4; ++j) {
        weq[j][0] = (_Float16)We[q4 + j];
        weq[j][1] = (_Float16)We[64 + q4 + j];
        beq[j] = be[q4 + j];
    }
    const float sj = g[c] * rsqrtf(rv[c] + BN_EPS);
    const float cj = (b[c] - rm[c]) * sj + bt[c];
    __syncthreads();

    // XCD swizzle: 4000 blocks = 8 XCDs x 500; same-XCD blocks -> contiguous nodes
    const int swz = (blockIdx.x & 7) * 500 + (blockIdx.x >> 3);
    const int wbase = (swz * 4 + w) * NPW;

    int offv[NPW + 1];
#pragma unroll
    for (int i = 0; i <= NPW; ++i) offv[i] = off[wbase + i];

    int2 rec0[NPW];                    // first-block records, all nodes
#pragma unroll
    for (int i = 0; i < NPW; ++i) {
        int2 r = make_int2(N_NODES, 0);
        if (c < offv[i + 1] - offv[i]) r = edges[offv[i] + c];
        rec0[i] = r;
    }

    int ldP[2][4], eyP[2][4];          // ping-pong chunk-0 gather sets
#define ISSUE(P, I)                                                              \
    {                                                                            \
        _Pragma("unroll")                                                        \
        for (int j = 0; j < 4; ++j) {                                            \
            int sx = __builtin_amdgcn_ds_bpermute(asb + (j << 4), rec0[I].x);    \
            eyP[P][j] = __builtin_amdgcn_ds_bpermute(asb + (j << 4), rec0[I].y); \
            ldP[P][j] = *(const int*)(hin8 + ((sx << 6) + dwoff));               \
        }                                                                        \
    }
#define CONSUME(LD, EA)                                                          \
    {                                                                            \
        h2vec av = __builtin_bit_cast(h2vec, EA);                                \
        float q0 = __builtin_amdgcn_fdot2(av, weq[0], beq[0], false);            \
        float q1 = __builtin_amdgcn_fdot2(av, weq[1], beq[1], false);            \
        float q2 = __builtin_amdgcn_fdot2(av, weq[2], beq[2], false);            \
        float q3 = __builtin_amdgcn_fdot2(av, weq[3], beq[3], false);            \
        acc0 += fmaxf(__builtin_amdgcn_cvt_f32_fp8(LD, 0) + q0, 0.f);            \
        acc1 += fmaxf(__builtin_amdgcn_cvt_f32_fp8(LD, 1) + q1, 0.f);            \
        acc2 += fmaxf(__builtin_amdgcn_cvt_f32_fp8(LD, 2) + q2, 0.f);            \
        acc3 += fmaxf(__builtin_amdgcn_cvt_f32_fp8(LD, 3) + q3, 0.f);            \
    }

    ISSUE(0, 0)
#pragma unroll
    for (int nn = 0; nn < NPW; ++nn) {
        const int p = nn & 1;
        if (nn + 1 < NPW) ISSUE(p ^ 1, nn + 1)   // overlap next node's chunk-0 gathers
        const int n = wbase + nn;
        const int rs = offv[nn], re = offv[nn + 1];
        const int cnt0 = min(64, re - rs);
        // conditional early chunk-1 (slots 16-31): wave-uniform branch, ~47% of nodes.
        int ldQ[4], eyQ[4];
        const bool hasQ = cnt0 > 16;
        if (hasQ) {
#pragma unroll
            for (int j = 0; j < 4; ++j) {
                const int ab = 64 + asb + (j << 4);
                int sx = __builtin_amdgcn_ds_bpermute(ab, rec0[nn].x);
                eyQ[j] = __builtin_amdgcn_ds_bpermute(ab, rec0[nn].y);
                ldQ[j] = *(const int*)(hin8 + ((sx << 6) + dwoff));
            }
        }
        const float hc = __half2float(hin[(size_t)n * 64 + c]);
        float acc0 = 0.f, acc1 = 0.f, acc2 = 0.f, acc3 = 0.f;
        CONSUME(ldP[p][0], eyP[p][0])
        CONSUME(ldP[p][1], eyP[p][1])
        CONSUME(ldP[p][2], eyP[p][2])
        CONSUME(ldP[p][3], eyP[p][3])
        if (hasQ) {
            CONSUME(ldQ[0], eyQ[0])
            CONSUME(ldQ[1], eyQ[1])
            CONSUME(ldQ[2], eyQ[2])
            CONSUME(ldQ[3], eyQ[3])
        }
        // remainder chunks of first block (deg > 32, ~0.01% of nodes)
        for (int j0 = 32; j0 < cnt0; j0 += 16) {
            const int ab = (j0 << 2) + asb;
            int s0 = __builtin_amdgcn_ds_bpermute(ab,      rec0[nn].x);
            int s1 = __builtin_amdgcn_ds_bpermute(ab + 16, rec0[nn].x);
            int s2 = __builtin_amdgcn_ds_bpermute(ab + 32, rec0[nn].x);
            int s3 = __builtin_amdgcn_ds_bpermute(ab + 48, rec0[nn].x);
            int e0 = __builtin_amdgcn_ds_bpermute(ab,      rec0[nn].y);
            int e1 = __builtin_amdgcn_ds_bpermute(ab + 16, rec0[nn].y);
            int e2 = __builtin_amdgcn_ds_bpermute(ab + 32, rec0[nn].y);
            int e3 = __builtin_amdgcn_ds_bpermute(ab + 48, rec0[nn].y);
            int ld0 = *(const int*)(hin8 + ((s0 << 6) + dwoff));
            int ld1 = *(const int*)(hin8 + ((s1 << 6) + dwoff));
            int ld2 = *(const int*)(hin8 + ((s2 << 6) + dwoff));
            int ld3 = *(const int*)(hin8 + ((s3 << 6) + dwoff));
            CONSUME(ld0, e0)
            CONSUME(ld1, e1)
            CONSUME(ld2, e2)
            CONSUME(ld3, e3)
        }
        // deg > 64 tail blocks (rare) — verbatim r3
        for (int base = rs + 64; base < re; base += 64) {
            const int cnt = min(64, re - base);
            int2 rec = make_int2(N_NODES, 0);
            if (c < cnt) rec = edges[base + c];
            for (int j0 = 0; j0 < cnt; j0 += 16) {
                const int ab = (j0 << 2) + asb;
                int s0 = __builtin_amdgcn_ds_bpermute(ab,      rec.x);
                int s1 = __builtin_amdgcn_ds_bpermute(ab + 16, rec.x);
                int s2 = __builtin_amdgcn_ds_bpermute(ab + 32, rec.x);
                int s3 = __builtin_amdgcn_ds_bpermute(ab + 48, rec.x);
                int e0 = __builtin_amdgcn_ds_bpermute(ab,      rec.y);
                int e1 = __builtin_amdgcn_ds_bpermute(ab + 16, rec.y);
                int e2 = __builtin_amdgcn_ds_bpermute(ab + 32, rec.y);
                int e3 = __builtin_amdgcn_ds_bpermute(ab + 48, rec.y);
                int ld0 = *(const int*)(hin8 + ((s0 << 6) + dwoff));
                int ld1 = *(const int*)(hin8 + ((s1 << 6) + dwoff));
                int ld2 = *(const int*)(hin8 + ((s2 << 6) + dwoff));
                int ld3 = *(const int*)(hin8 + ((s3 << 6) + dwoff));
                CONSUME(ld0, e0)
                CONSUME(ld1, e1)
                CONSUME(ld2, e2)
                CONSUME(ld3, e3)
            }
        }
        // fold 4 edge-slot groups (lane bits 4,5)
        acc0 += __shfl_xor(acc0, 16); acc1 += __shfl_xor(acc1, 16);
        acc2 += __shfl_xor(acc2, 16); acc3 += __shfl_xor(acc3, 16);
        acc0 += __shfl_xor(acc0, 32); acc1 += __shfl_xor(acc1, 32);
        acc2 += __shfl_xor(acc2, 32); acc3 += __shfl_xor(acc3, 32);
        h4vec aq = {(_Float16)acc0, (_Float16)acc1, (_Float16)acc2, (_Float16)acc3};
        *(h4vec*)&uL[w][q4] = aq;            // duplicate writers, same value
        float u = hc + (float)uL[w][c];      // per-channel center add
        uL[w][c] = (_Float16)u;
        float z = 0.f;
        const h4vec* u4p = (const h4vec*)uL[w];
        const h4vec* wt4p = (const h4vec*)&WtL[c][0];
#pragma unroll
        for (int k4 = 0; k4 < 16; ++k4) {
            h4vec uu = u4p[k4];
            h4vec ww = wt4p[k4];
            h2vec ul = __builtin_shufflevector(uu, uu, 0, 1);
            h2vec uh = __builtin_shufflevector(uu, uu, 2, 3);
            h2vec wl = __builtin_shufflevector(ww, ww, 0, 1);
            h2vec wh = __builtin_shufflevector(ww, ww, 2, 3);
            z = __builtin_amdgcn_fdot2(ul, wl, z, false);
            z = __builtin_amdgcn_fdot2(uh, wh, z, false);
        }
        float v = fmaxf(fmaf(z, sj, cj), 0.f) + hc;
        hout[(size_t)n * 64 + c] = __float2half(v);
        hout8[(size_t)n * 64 + c] = f32_to_fp8(v);
    }
#undef CONSUME
#undef ISSUE
}

// ---------------- Pool (mean+max per graph) + classifier ----------------
__global__ __launch_bounds__(256) void k_pool(
    const __half* __restrict__ h, const int* __restrict__ batch,
    const float* __restrict__ Wc1, const float* __restrict__ bc1,
    const float* __restrict__ Wc2, const float* __restrict__ bc2,
    float* __restrict__ out) {
    __shared__ float psum[4][64];
    __shared__ float pmax[4][64];
    __shared__ float pool[128];
    __shared__ float hid[64];
    const int t = threadIdx.x, w = t >> 6, c = t & 63;
    const int g = blockIdx.x;
    int lo = 0, hi = N_NODES;
    while (lo < hi) { int mid = (lo + hi) >> 1; if (batch[mid] < g) lo = mid + 1; else hi = mid; }
    int start = lo;
    hi = N_NODES;
    while (lo < hi) { int mid = (lo + hi) >> 1; if (batch[mid] < g + 1) lo = mid + 1; else hi = mid; }
    int end = lo;

    float s = 0.f, m = -3.4e38f;
    for (int i = start + w; i < end; i += 4) {
        float v = __half2float(h[(size_t)i * 64 + c]);
        s += v;
        m = fmaxf(m, v);
    }
    psum[w][c] = s;
    pmax[w][c] = m;
    __syncthreads();
    if (w == 0) {
        float ss = psum[0][c] + psum[1][c] + psum[2][c] + psum[3][c];
        float mm = fmaxf(fmaxf(pmax[0][c], pmax[1][c]), fmaxf(pmax[2][c], pmax[3][c]));
        int cnt = end - start;
        pool[c] = ss / fmaxf((float)cnt, 1.f);
        pool[64 + c] = (cnt > 0) ? mm : 0.f;
    }
    __syncthreads();
    if (t < 64) {
        float z = bc1[t];
#pragma unroll 8
        for (int k = 0; k < 128; ++k) z = fmaf(pool[k], Wc1[k * 64 + t], z);
        hid[t] = fmaxf(z, 0.f);
    }
    __syncthreads();
    if (t < N_CLS) {
        float z = bc2[t];
#pragma unroll
        for (int k = 0; k < 64; ++k) z = fmaf(hid[k], Wc2[k * N_CLS + t], z);
        out[g * N_CLS + t] = z;
    }
}

extern "C" void kernel_launch(void* const* d_in, const int* in_sizes, int n_in,
                              void* d_out, int out_size, void* d_ws, size_t ws_size,
                              hipStream_t stream) {
    const float* x     = (const float*)d_in[0];
    const int*   ei    = (const int*)d_in[1];
    const float* ea    = (const float*)d_in[2];
    const int*   batch = (const int*)d_in[3];
    const float* We1 = (const float*)d_in[4],  *be1 = (const float*)d_in[5];
    const float* We2 = (const float*)d_in[6],  *be2 = (const float*)d_in[7];
    const float* We3 = (const float*)d_in[8],  *be3 = (const float*)d_in[9];
    const float* W1 = (const float*)d_in[10], *b1 = (const float*)d_in[11];
    const float* g1 = (const float*)d_in[12], *bt1 = (const float*)d_in[13];
    const float* rm1 = (const float*)d_in[14], *rv1 = (const float*)d_in[15];
    const float* W2 = (const float*)d_in[16], *b2 = (const float*)d_in[17];
    const float* g2 = (const float*)d_in[18], *bt2 = (const float*)d_in[19];
    const float* rm2 = (const float*)d_in[20], *rv2 = (const float*)d_in[21];
    const float* W3 = (const float*)d_in[22], *b3 = (const float*)d_in[23];
    const float* g3 = (const float*)d_in[24], *bt3 = (const float*)d_in[25];
    const float* rm3 = (const float*)d_in[26], *rv3 = (const float*)d_in[27];
    const float* Wr = (const float*)d_in[28], *br = (const float*)d_in[29];
    const float* Wc1 = (const float*)d_in[30], *bc1 = (const float*)d_in[31];
    const float* Wc2 = (const float*)d_in[32], *bc2 = (const float*)d_in[33];

    int* off    = (int*)d_ws;                   // N+4
    int* gcount = off + (N_NODES + 4);          // 1024 (NB=1000, zero-padded)
    int* bbase  = gcount + 1024;                // 1024
    int2* edges = (int2*)(bbase + 1024);        // E * 8B packed records
    int2* stage = edges + E_EDGES;              // NB*BCAP * 8B fixed bucket regions
    __half* hA  = (__half*)(stage + (size_t)NB * BCAP);  // N*64 fp16
    __half* hB  = hA + (size_t)N_NODES * 64;    // N*64 fp16
    unsigned char* hA8 = (unsigned char*)(hB + (size_t)N_NODES * 64);  // (N+1)*64 fp8
    unsigned char* hB8 = hA8 + (size_t)(N_NODES + 1) * 64;             // (N+1)*64 fp8
    __half* x16 = (__half*)(hB8 + (size_t)(N_NODES + 1) * 64);         // (N+1)*16 fp16

    hipMemsetAsync(gcount, 0, 1024 * sizeof(int), stream);
    // sentinel fp8 rows: 0xFE = -448 e4m3fn -> ReLU kills tail-edge messages
    hipMemsetAsync(hA8 + (size_t)N_NODES * 64, 0xFE, 64, stream);
    hipMemsetAsync(hB8 + (size_t)N_NODES * 64, 0xFE, 64, stream);

    const int* src = ei;
    const int* dst = ei + E_EDGES;

    k_pack_x<<<((N_NODES + 1) * 16 + 255) / 256, 256, 0, stream>>>(x, x16);
    k_bin<<<E_EDGES / TILE, 512, 0, stream>>>(src, dst, (const float2*)ea, gcount, stage);
    k_bscan<<<1, 256, 0, stream>>>(gcount, bbase, off);
    k_final<<<NB, 256, 0, stream>>>(gcount, bbase, stage, off, edges);

    k_gine12<<<N_NODES / (4 * NPW12), 256, 0, stream>>>(x, x16, hA, hA8, off, edges,
                                                        We1, be1, W1, b1, g1, bt1, rm1, rv1, Wr, br);
    const int g64_blocks = N_NODES / (4 * NPW);  // 4000
    k_gine64<<<g64_blocks, 256, 0, stream>>>(hA, hA8, hB, hB8, off, edges,
                                             We2, be2, W2, b2, g2, bt2, rm2, rv2);
    k_gine64<<<g64_blocks, 256, 0, stream>>>(hB, hB8, hA, hA8, off, edges,
                                             We3, be3, W3, b3, g3, bt3, rm3, rv3);
    k_pool<<<G_GRAPHS, 256, 0, stream>>>(hA, batch, Wc1, bc1, Wc2, bc2, (float*)d_out);
}